// Round 14
// baseline (1790.988 us; speedup 1.0000x reference)
//
#include <hip/hip_runtime.h>
#include <hip/hip_cooperative_groups.h>
#include <stdint.h>

namespace cg = cooperative_groups;

// DualPrimalEdgePooling on MI355X — 11 dispatches.
// zero -> 4x radix-hist -> cooperative mega-kernel (seed, ties, worklist CC
// with fused jump, flatten, rank scan, cluster/counts, counts2 scan, scatter)
// -> fused segmean+edges -> bitmap scan x2 -> dualacc -> finalize.

#define N_NODES 200000
#define N_EDGES 600000
#define FDIM 128
#define NUM_POOL 300000u  // = E - NUM_KEEP

#define SC_NEEDEQ 3
#define SC_TIECNT 4
#define SC_C 5
#define SC_W 6
#define SC_U 7
#define SC_VCNT 8
#define SC_WL0 16        // per-round worklist counters: slots 16..24 (never reset)
#define TIECAP 4096
#define WLCAP 300800
#define HB 256           // hist grid blocks
#define NSB 98           // ceil(N/2048)
#define NSHAD 8          // psum shadow copies (atomic-depth divider)
#define NSHAD2 16        // scatter cursor shadows
#define CMAX 16384       // max clusters supported (bitmap/pair-key bound)
#define SROWS 128        // rows per wave in segsum
#define SGB 391          // ceil(N/(SROWS*4)) segsum blocks
#define CGB 1024         // cooperative grid blocks

__device__ __forceinline__ uint32_t f2ou(float f){
  uint32_t b = __float_as_uint(f);
  return (b & 0x80000000u) ? ~b : (b | 0x80000000u);
}
__device__ __forceinline__ uint32_t ld_ag(const uint32_t* p){
  return __hip_atomic_load(p, __ATOMIC_RELAXED, __HIP_MEMORY_SCOPE_AGENT);
}

// block-wide digit selection from a completed 256-bin histogram (blockDim=256)
static __device__ __forceinline__ void sel_level(const uint32_t* hist, uint32_t& target,
                                                 uint32_t& pfx, uint32_t* sm, uint32_t* res){
  int t = threadIdx.x;
  uint32_t cnt = hist[t];
  sm[t] = cnt; __syncthreads();
  for(int off = 1; off < 256; off <<= 1){
    uint32_t y = (t + off < 256) ? sm[t + off] : 0u;
    __syncthreads(); sm[t] += y; __syncthreads();
  }
  uint32_t suffix = sm[t];            // candidates with digit >= t
  uint32_t above  = suffix - cnt;
  if(above < target && target <= suffix){ res[0] = (uint32_t)t; res[1] = target - above; }
  __syncthreads();
  pfx = (pfx << 8) | res[0];
  target = res[1];
  __syncthreads();
}

// block-wide exclusive scan of one value per thread (blockDim=256); ends synced
static __device__ __forceinline__ uint32_t blk_excl(uint32_t v, uint32_t* sm, uint32_t& total){
  int t = threadIdx.x;
  sm[t] = v; __syncthreads();
  for(int off = 1; off < 256; off <<= 1){
    uint32_t y = (t >= off) ? sm[t - off] : 0u;
    __syncthreads(); sm[t] += y; __syncthreads();
  }
  total = sm[255];
  uint32_t incl = sm[t];
  __syncthreads();
  return incl - v;
}

// ---- tiny ws zero (sc + hists + counts + counts2), vectorized ----
__global__ __launch_bounds__(256) void k_zero(uint4* w4, uint32_t n4){
  uint32_t gid = blockIdx.x*256 + threadIdx.x;
  uint4 z = make_uint4(0u,0u,0u,0u);
  for(uint32_t j = gid; j < n4; j += gridDim.x*256) w4[j] = z;
}

// ---- selection: 4-level 8-bit radix histograms; prior-level digits recomputed in-block ----
template<int LEVEL>
__global__ __launch_bounds__(256) void k_hist8(const float* att, uint32_t* hists, int* L){
  __shared__ uint32_t h[256];
  __shared__ uint32_t sm[256];
  __shared__ uint32_t res[2];
  h[threadIdx.x] = 0;
  if(LEVEL == 1){
    for(int i = blockIdx.x*256 + threadIdx.x; i < N_NODES; i += HB*256) L[i] = i;  // fused CC init
  }
  __syncthreads();
  uint32_t pfx = 0, target = NUM_POOL;
  #pragma unroll
  for(int l = 0; l < LEVEL-1; ++l) sel_level(hists + 256*l, target, pfx, sm, res);
  constexpr int SH1 = (LEVEL > 1) ? 8*(5-LEVEL) : 0;
  constexpr int SH2 = 8*(4-LEVEL);
  for(int e = blockIdx.x*256 + threadIdx.x; e < N_EDGES; e += HB*256){
    uint32_t u = f2ou(att[e]);
    bool ok = (LEVEL == 1) || ((u >> SH1) == pfx);
    if(ok) atomicAdd(&h[(u >> SH2) & 0xFFu], 1u);
  }
  __syncthreads();
  uint32_t c = h[threadIdx.x];
  if(c) atomicAdd(&hists[256*(LEVEL-1) + threadIdx.x], c);
}

// ---- cooperative mega-kernel: seed .. scatter (no early returns; uniform syncs) ----
__global__ __launch_bounds__(256) void k_mega(const float* att, const int* src, const int* dst,
      const uint32_t* hists, uint32_t* sc, uint32_t* tieIdx, int* L,
      uint2* wl0, uint2* wl1, uint32_t* bsums, uint32_t* rank_, int* cluster_i,
      float* outC, uint32_t* counts, uint32_t* counts2, float* psumS,
      uint32_t* bitmap, uint32_t* cursor2, uint32_t* order){
  cg::grid_group grid = cg::this_grid();
  __shared__ uint32_t sm[256];
  __shared__ uint32_t res[2];
  __shared__ uint32_t basesh;
  const uint32_t tid = threadIdx.x;
  const uint32_t gid = blockIdx.x*256u + tid;
  const uint32_t GS  = CGB*256u;
  const int lane = (int)(tid & 63);

  // threshold recompute (all blocks; hists are LLC-hot)
  uint32_t pfx = 0, target = NUM_POOL;
  #pragma unroll
  for(int l = 0; l < 4; ++l) sel_level(hists + 256*l, target, pfx, sm, res);
  if(gid == 0) sc[SC_NEEDEQ] = target;
  const uint32_t T = pfx;

  // phase A: seed — hook pooled edges, block-agg worklist append, record ties
  for(uint32_t e0 = blockIdx.x*256u; e0 < N_EDGES; e0 += GS){
    uint32_t e = e0 + tid;
    bool app = false; int u = 0, v = 0;
    if(e < N_EDGES){
      uint32_t ub = f2ou(att[e]);
      if(ub > T){
        u = src[e]; v = dst[e];
        if(u != v){ int m = u < v ? u : v, hi = u ^ v ^ m; atomicMin(&L[hi], m); app = true; }
      } else if(ub == T){
        uint32_t p = atomicAdd(&sc[SC_TIECNT], 1u);
        if(p < TIECAP) tieIdx[p] = e;
      }
    }
    uint32_t tot, off = blk_excl(app ? 1u : 0u, sm, tot);
    if(tid == 0 && tot) basesh = atomicAdd(&sc[SC_WL0], tot);
    __syncthreads();
    if(app) wl0[basesh + off] = make_uint2((uint32_t)(u < v ? u : v), (uint32_t)(u > v ? u : v));
    __syncthreads();
  }
  grid.sync();

  // phase A2: tie selection (block 0; stable argsort = smallest indices pooled)
  if(blockIdx.x == 0){
    uint32_t m = sc[SC_TIECNT]; if(m > TIECAP) m = TIECAP;
    uint32_t need = sc[SC_NEEDEQ];
    for(uint32_t i0 = 0; i0 < m; i0 += 256){
      uint32_t i = i0 + tid;
      bool app = false; int u = 0, v = 0;
      if(i < m){
        uint32_t mine = tieIdx[i];
        uint32_t rr = 0;
        for(uint32_t j = 0; j < m; j++) rr += (tieIdx[j] < mine) ? 1u : 0u;
        if(rr < need){
          u = src[mine]; v = dst[mine];
          if(u != v){ int mm = u < v ? u : v, hi = u ^ v ^ mm; atomicMin(&L[hi], mm); app = true; }
        }
      }
      uint32_t tot, off = blk_excl(app ? 1u : 0u, sm, tot);
      if(tid == 0 && tot) basesh = atomicAdd(&sc[SC_WL0], tot);
      __syncthreads();
      if(app) wl0[basesh + off] = make_uint2((uint32_t)(u < v ? u : v), (uint32_t)(u > v ? u : v));
      __syncthreads();
    }
  }
  grid.sync();

  // phase B: relax rounds (4-level chase + hooking atomicMin + block-agg re-append),
  // fused monotone jump (atomicMin), grid-uniform early break on empty worklist.
  for(int r = 1; r <= 8; ++r){
    uint32_t n = ld_ag(&sc[SC_WL0 + r - 1]);
    if(n == 0) break;   // uniform: counter finalized before last grid.sync
    const uint2* win = (r & 1) ? wl0 : wl1;
    uint2* wout      = (r & 1) ? wl1 : wl0;
    for(uint32_t base = blockIdx.x*256u; base < n; base += GS){
      uint32_t idx = base + tid;
      bool active = idx < n;
      int lu = 0, lv = 0;
      if(active){
        uint2 ed = win[idx];
        lu = L[ed.x]; lu = L[lu]; lu = L[lu]; lu = L[lu];
        lv = L[ed.y]; lv = L[lv]; lv = L[lv]; lv = L[lv];
        active = (lu != lv);
        if(active){ int m = lu < lv ? lu : lv, hi = lu ^ lv ^ m; atomicMin(&L[hi], m); }
      }
      uint32_t tot, off = blk_excl(active ? 1u : 0u, sm, tot);
      if(tid == 0 && tot) basesh = atomicAdd(&sc[SC_WL0 + r], tot);
      __syncthreads();
      if(active) wout[basesh + off] = make_uint2((uint32_t)(lu < lv ? lu : lv),
                                                 (uint32_t)(lu > lv ? lu : lv));
      __syncthreads();
    }
    for(uint32_t i = gid; i < N_NODES; i += GS){
      int v = L[i]; v = L[v]; v = L[v]; v = L[v];
      if(v < (int)i) atomicMin(&L[i], v);
    }
    grid.sync();
  }

  // phase C: flatten to roots + per-chunk root counts (2048 nodes/chunk)
  for(uint32_t chunk = blockIdx.x; chunk < NSB; chunk += CGB){
    uint32_t base = chunk*2048u + tid*8u;
    uint32_t s = 0;
    #pragma unroll
    for(int k = 0; k < 8; k++){
      uint32_t i = base + k;
      if(i < N_NODES){
        int p = L[i]; int q = L[p];
        while(q != p){ p = q; q = L[p]; }
        L[i] = p;
        s += (p == (int)i) ? 1u : 0u;
      }
    }
    sm[tid] = s; __syncthreads();
    for(int off = 128; off > 0; off >>= 1){
      if((int)tid < off) sm[tid] += sm[tid + off];
      __syncthreads();
    }
    if(tid == 0) bsums[chunk] = sm[0];
    __syncthreads();
  }
  grid.sync();

  // phase D1: block 0 exclusive-scans the NSB chunk sums -> SC_C, SC_W
  if(blockIdx.x == 0){
    uint32_t v = (tid < NSB) ? bsums[tid] : 0u;
    uint32_t tot, excl = blk_excl(v, sm, tot);
    if(tid < NSB) bsums[tid] = excl;
    if(tid == 0){ sc[SC_C] = tot; uint64_t cc = (uint64_t)tot*tot; sc[SC_W] = (uint32_t)((cc + 31ull) >> 5); }
  }
  grid.sync();

  // phase D2: rank_ = exclusive prefix of root flags
  for(uint32_t chunk = blockIdx.x; chunk < NSB; chunk += CGB){
    uint32_t base = chunk*2048u + tid*8u;
    uint32_t xs[8]; uint32_t ts = 0;
    #pragma unroll
    for(int k = 0; k < 8; k++){
      uint32_t idx = base + k;
      uint32_t v = (idx < N_NODES && L[idx] == (int)idx) ? 1u : 0u;
      xs[k] = v; ts += v;
    }
    uint32_t tot, excl = blk_excl(ts, sm, tot);
    uint32_t run = bsums[chunk] + excl;
    #pragma unroll
    for(int k = 0; k < 8; k++){ uint32_t idx = base + k; if(idx < N_NODES) rank_[idx] = run; run += xs[k]; }
    __syncthreads();
  }
  grid.sync();

  // phase E: cluster ids + wave-agg counts/counts2 + lazy zero psumS/bitmap
  {
    uint32_t C = ld_ag(&sc[SC_C]);
    uint32_t W = ld_ag(&sc[SC_W]);
    float4* p4 = (float4*)psumS;
    float4 z = make_float4(0.f,0.f,0.f,0.f);
    for(size_t j = gid; j < (size_t)NSHAD*C*(FDIM/4); j += GS) p4[j] = z;
    for(uint32_t j = gid; j < W; j += GS) bitmap[j] = 0u;
  }
  for(uint32_t base = blockIdx.x*256u; base < N_NODES; base += GS){
    uint32_t i0 = base + tid;
    bool act = i0 < N_NODES;
    int c = -1;
    if(act){
      c = (int)rank_[L[i0]];
      cluster_i[i0] = c;
      outC[i0] = (float)c;
    }
    int sh = (int)((i0 >> 6) & (NSHAD2-1));   // wave-uniform (64-aligned base)
    unsigned long long remaining = __ballot(act);
    while(remaining){
      int leader = __ffsll(remaining) - 1;
      int lc = __shfl(c, leader);
      unsigned long long grp = __ballot(c == lc) & remaining;
      if(lane == leader){
        uint32_t cnt = (uint32_t)__popcll(grp);
        atomicAdd(&counts[lc], cnt);
        atomicAdd(&counts2[lc*NSHAD2 + sh], cnt);
      }
      remaining &= ~grp;
    }
  }
  grid.sync();

  // phase F: counts2 -> cursor2 (3-step scan; n2 = C*16, <=128 chunks)
  uint32_t C = ld_ag(&sc[SC_C]);
  uint32_t n2 = C*NSHAD2;
  uint32_t nch = (n2 + 2047u) >> 11;
  for(uint32_t chunk = blockIdx.x; chunk < nch; chunk += CGB){
    uint32_t base = chunk*2048u + tid*8u;
    uint32_t s = 0;
    #pragma unroll
    for(int k = 0; k < 8; k++){ uint32_t idx = base + k; if(idx < n2) s += counts2[idx]; }
    sm[tid] = s; __syncthreads();
    for(int off = 128; off > 0; off >>= 1){
      if((int)tid < off) sm[tid] += sm[tid + off];
      __syncthreads();
    }
    if(tid == 0) bsums[chunk] = sm[0];
    __syncthreads();
  }
  grid.sync();
  if(blockIdx.x == 0){
    uint32_t v = (tid < nch) ? bsums[tid] : 0u;
    uint32_t tot, excl = blk_excl(v, sm, tot);
    if(tid < nch) bsums[tid] = excl;
  }
  grid.sync();
  for(uint32_t chunk = blockIdx.x; chunk < nch; chunk += CGB){
    uint32_t base = chunk*2048u + tid*8u;
    uint32_t xs[8]; uint32_t ts = 0;
    #pragma unroll
    for(int k = 0; k < 8; k++){ uint32_t idx = base + k; uint32_t v = (idx < n2) ? counts2[idx] : 0u; xs[k] = v; ts += v; }
    uint32_t tot, excl = blk_excl(ts, sm, tot);
    uint32_t run = bsums[chunk] + excl;
    #pragma unroll
    for(int k = 0; k < 8; k++){ uint32_t idx = base + k; if(idx < n2) cursor2[idx] = run; run += xs[k]; }
    __syncthreads();
  }
  grid.sync();

  // phase G: counting-sort scatter via 16-shadow cursors (same sh mapping as phase E)
  for(uint32_t base = blockIdx.x*256u; base < N_NODES; base += GS){
    uint32_t i0 = base + tid;
    bool act = i0 < N_NODES;
    int c = act ? cluster_i[i0] : -1;
    int sh = (int)((i0 >> 6) & (NSHAD2-1));
    unsigned long long remaining = __ballot(act);
    while(remaining){
      int leader = __ffsll(remaining) - 1;
      int lc = __shfl(c, leader);
      unsigned long long grp = __ballot(c == lc) & remaining;
      int b = 0;
      if(lane == leader) b = (int)atomicAdd(&cursor2[lc*NSHAD2 + sh], (uint32_t)__popcll(grp));
      b = __shfl(b, leader);
      if((grp >> lane) & 1ull){
        uint32_t sub = (uint32_t)__popcll(grp & ((1ull << lane) - 1ull));
        order[(uint32_t)b + sub] = i0;
      }
      remaining &= ~grp;
    }
  }
}

// ---- 2-kernel bitmap scan (MODE 1 only): popc(bitmap)->wpref (+SC_U) ----
__global__ __launch_bounds__(256) void k_scan_reduce1(const uint32_t* in, uint32_t* bsums,
                       const uint32_t* sc, float* dsum, uint32_t* dcnt){
  uint32_t n = sc[SC_W];
  {  // lazy-zero compact dual accumulators (VCNT rows >= U), vectorized
    uint32_t vc = sc[SC_VCNT];
    size_t gid = (size_t)blockIdx.x*256 + threadIdx.x, gs = (size_t)gridDim.x*256;
    float4* d4 = (float4*)dsum;
    float4 z = make_float4(0.f,0.f,0.f,0.f);
    for(size_t j = gid; j < (size_t)vc*(FDIM/4); j += gs) d4[j] = z;
    for(size_t j = gid; j < vc; j += gs) dcnt[j] = 0u;
  }
  uint32_t base = blockIdx.x*2048u + threadIdx.x*8u;
  uint32_t s = 0;
  #pragma unroll
  for(int k = 0; k < 8; k++){
    uint32_t idx = base + k;
    if(idx < n) s += __popc(in[idx]);
  }
  __shared__ uint32_t sm[256];
  sm[threadIdx.x] = s; __syncthreads();
  for(int off = 128; off > 0; off >>= 1){
    if((int)threadIdx.x < off) sm[threadIdx.x] += sm[threadIdx.x + off];
    __syncthreads();
  }
  if(threadIdx.x == 0) bsums[blockIdx.x] = sm[0];
}
__global__ __launch_bounds__(256) void k_scan_apply1(const uint32_t* in, const uint32_t* bsums,
                       int nb, uint32_t* out, uint32_t* sc){
  __shared__ uint32_t bs[4096];
  __shared__ uint32_t sm[256];
  int t = threadIdx.x;
  uint32_t n = sc[SC_W];
  uint32_t loc[16]; uint32_t ls = 0;
  #pragma unroll
  for(int k = 0; k < 16; k++){ int idx = t*16 + k; uint32_t v = (idx < nb) ? bsums[idx] : 0u; loc[k] = v; ls += v; }
  sm[t] = ls; __syncthreads();
  for(int off = 1; off < 256; off <<= 1){
    uint32_t y = (t >= off) ? sm[t - off] : 0u;
    __syncthreads(); sm[t] += y; __syncthreads();
  }
  uint32_t total = sm[255];
  uint32_t run = sm[t] - ls;
  #pragma unroll
  for(int k = 0; k < 16; k++){ bs[t*16 + k] = run; run += loc[k]; }
  __syncthreads();
  uint32_t blockbase = bs[blockIdx.x];
  __syncthreads();
  uint32_t base = blockIdx.x*2048u + t*8u;
  uint32_t xs[8]; uint32_t ts2 = 0;
  #pragma unroll
  for(int k = 0; k < 8; k++){
    uint32_t idx = base + k;
    uint32_t v = (idx < n) ? __popc(in[idx]) : 0u;
    xs[k] = v; ts2 += v;
  }
  sm[t] = ts2; __syncthreads();
  for(int off = 1; off < 256; off <<= 1){
    uint32_t y = (t >= off) ? sm[t - off] : 0u;
    __syncthreads(); sm[t] += y; __syncthreads();
  }
  uint32_t run2 = blockbase + sm[t] - ts2;
  #pragma unroll
  for(int k = 0; k < 8; k++){ uint32_t idx = base + k; if(idx < n) out[idx] = run2; run2 += xs[k]; }
  if(blockIdx.x == 0 && t == 0) sc[SC_U] = total;
}

// ---- fused: segmented mean into 8-shadow psum (blocks < SGB) | edges+bitmap (rest) ----
__global__ __launch_bounds__(256) void k_seg_edges(const float* px, const uint32_t* order,
        const int* cluster_i, float* psumS, const int* src, const int* dst, uint32_t* sc,
        float* outE, uint32_t* kc, uint32_t* bitmap){
  if(blockIdx.x < SGB){
    int wave = (int)((blockIdx.x*256u + threadIdx.x) >> 6);
    int lane = threadIdx.x & 63;
    int start = wave * SROWS;
    if(start >= N_NODES) return;
    int cnt = N_NODES - start; if(cnt > SROWS) cnt = SROWS;
    size_t shadBase = (size_t)(wave & (NSHAD-1)) * (size_t)sc[SC_C] * FDIM;
    uint32_t ord0 = 0, ord1 = 0; int c0 = -1, c1 = -1;
    if(lane < cnt){ ord0 = order[start + lane]; c0 = cluster_i[ord0]; }
    if(64 + lane < cnt){ ord1 = order[start + 64 + lane]; c1 = cluster_i[ord1]; }
    float ax = 0.f, ay = 0.f; int cur = -1;
    for(int r = 0; r < cnt; r++){
      uint32_t i; int c;
      if(r < 64){ i = (uint32_t)__shfl((int)ord0, r); c = __shfl(c0, r); }
      else      { i = (uint32_t)__shfl((int)ord1, r - 64); c = __shfl(c1, r - 64); }
      if(c != cur){
        if(cur >= 0){
          atomicAdd(&psumS[shadBase + (size_t)cur*FDIM + 2*lane], ax);
          atomicAdd(&psumS[shadBase + (size_t)cur*FDIM + 2*lane + 1], ay);
        }
        cur = c; ax = 0.f; ay = 0.f;
      }
      float2 v = ((const float2*)(px + (size_t)i*FDIM))[lane];
      ax += v.x; ay += v.y;
    }
    if(cur >= 0){
      atomicAdd(&psumS[shadBase + (size_t)cur*FDIM + 2*lane], ax);
      atomicAdd(&psumS[shadBase + (size_t)cur*FDIM + 2*lane + 1], ay);
    }
  } else {
    __shared__ uint32_t wsum[4];
    int e = (blockIdx.x - SGB)*256 + threadIdx.x;
    int lane = threadIdx.x & 63;
    int wv = threadIdx.x >> 6;
    bool val = false;
    if(e < N_EDGES){
      int cu = cluster_i[src[e]];
      int cv = cluster_i[dst[e]];
      val = (cu != cv);
      outE[e] = val ? (float)cu : -1.0f;
      outE[N_EDGES + e] = val ? (float)cv : -1.0f;
      if(val){
        int a = cu < cv ? cu : cv, b = cu < cv ? cv : cu;
        uint32_t C = sc[SC_C];
        uint32_t key = (uint32_t)a * C + (uint32_t)b;
        kc[e] = key;
        atomicOr(&bitmap[key >> 5], 1u << (key & 31u));
      } else {
        kc[e] = 0xFFFFFFFFu;
      }
    }
    unsigned long long grp = __ballot(val);
    if(lane == 0) wsum[wv] = (uint32_t)__popcll(grp);
    __syncthreads();
    if(threadIdx.x == 0){
      uint32_t s = wsum[0] + wsum[1] + wsum[2] + wsum[3];
      if(s) atomicAdd(&sc[SC_VCNT], s);   // fire-and-forget (upper bound for dsum zeroing)
    }
  }
}

// ---- dual accumulate: 64 edges/wave, ballot + shfl-broadcast rank ----
__global__ __launch_bounds__(256) void k_dualacc(const float* dx, const uint32_t* kc,
                          const uint32_t* bitmap, const uint32_t* wpref,
                          float* dsum, uint32_t* dcnt){
  int wave = (int)((blockIdx.x*256u + threadIdx.x) >> 6);
  int lane = threadIdx.x & 63;
  int base = wave * 64;
  if(base >= N_EDGES) return;
  int e = base + lane;
  uint32_t key = (e < N_EDGES) ? kc[e] : 0xFFFFFFFFu;
  bool val = (key != 0xFFFFFFFFu);
  uint32_t r = 0;
  if(val){
    uint32_t wi = key >> 5, bi = key & 31u;
    r = wpref[wi] + __popc(bitmap[wi] & ((1u << bi) - 1u));
  }
  unsigned long long m = __ballot(val);
  while(m){
    int b = __ffsll(m) - 1;
    m &= m - 1;
    uint32_t ee = (uint32_t)(base + b);
    uint32_t rr = (uint32_t)__shfl((int)r, b);
    float2 v = ((const float2*)(dx + (size_t)ee*FDIM))[lane];
    atomicAdd(&dsum[(size_t)rr*FDIM + 2*lane], v.x);
    atomicAdd(&dsum[(size_t)rr*FDIM + 2*lane + 1], v.y);
    if(lane == 0) atomicAdd(&dcnt[rr], 1u);
  }
}
// ---- stream the full output region: shadow-summed means for live rows, zeros elsewhere ----
__global__ __launch_bounds__(256) void k_finalize(const float4* psumS, const uint32_t* counts,
        const float4* dsum, const uint32_t* dcnt, const uint32_t* sc, float4* out4){
  uint32_t C = sc[SC_C], U = sc[SC_U];
  size_t cs = (size_t)C * (FDIM/4);          // shadow stride in float4
  size_t gid = (size_t)blockIdx.x*256 + threadIdx.x;
  size_t gs = (size_t)gridDim.x*256;
  const size_t NP4 = (size_t)N_NODES*(FDIM/4);
  const size_t TOT4 = (size_t)(N_NODES + N_EDGES)*(FDIM/4);
  for(size_t j = gid; j < TOT4; j += gs){
    float4 v = make_float4(0.f,0.f,0.f,0.f);
    if(j < NP4){
      uint32_t r = (uint32_t)(j >> 5);
      if(r < C){
        v = psumS[j];
        #pragma unroll
        for(int s = 1; s < NSHAD; s++){
          float4 t = psumS[(size_t)s*cs + j];
          v.x += t.x; v.y += t.y; v.z += t.z; v.w += t.w;
        }
        float fc = (float)counts[r];
        v.x /= fc; v.y /= fc; v.z /= fc; v.w /= fc;
      }
    } else {
      size_t dj = j - NP4;
      uint32_t r = (uint32_t)(dj >> 5);
      if(r < U){
        v = dsum[dj];
        float fc = (float)dcnt[r];
        v.x /= fc; v.y /= fc; v.z /= fc; v.w /= fc;
      }
    }
    out4[j] = v;
  }
}

extern "C" void kernel_launch(void* const* d_in, const int* in_sizes, int n_in,
                              void* d_out, int out_size, void* d_ws, size_t ws_size,
                              hipStream_t stream){
  (void)in_sizes; (void)n_in; (void)out_size;
  const float* primal_x = (const float*)d_in[0];
  const float* dual_x   = (const float*)d_in[1];
  const float* att      = (const float*)d_in[2];
  const int*   pei      = (const int*)d_in[3];
  const int* src = pei;
  const int* dst = pei + N_EDGES;

  float* out  = (float*)d_out;
  float* outE = out + (size_t)(N_NODES + N_EDGES)*FDIM;   // (2, E)
  float* outC = outE + (size_t)2*N_EDGES;                 // (N,)

  uint32_t* w = (uint32_t*)d_ws;
  size_t words_avail = ws_size / 4;
  const size_t PSUMW = (size_t)NSHAD*CMAX*FDIM;            // 16.8M words
  const size_t CNT2W = (size_t)CMAX*NSHAD2;                // 262144 words
  const size_t FIXED = 64 + 1024 + (size_t)N_NODES + CNT2W
                     + TIECAP + 4*(size_t)N_NODES + CNT2W + 4*(size_t)WLCAP
                     + (size_t)N_EDGES + (size_t)N_EDGES   // kc + dcnt
                     + 4096
                     + PSUMW + (size_t)N_EDGES*FDIM;       // psumS + dsum
  size_t wcap = (words_avail > FIXED) ? (words_avail - FIXED)/2 : 4;
  if(wcap > 8388608) wcap = 8388608;   // supports C up to 16384
  wcap &= ~(size_t)3;

  size_t o = 0;
  uint32_t* sc      = w;               o += 64;
  uint32_t* hists   = w + o;           o += 1024;          // 4 x 256
  uint32_t* counts  = w + o;           o += N_NODES;
  uint32_t* counts2 = w + o;           o += CNT2W;
  size_t zero_words = o;                                    // zeroed per call (mult of 4)
  uint32_t* tieIdx  = w + o;           o += TIECAP;
  int* labels       = (int*)(w + o);   o += N_NODES;
  uint32_t* rank_   = w + o;           o += N_NODES;
  int* cluster_i    = (int*)(w + o);   o += N_NODES;
  uint32_t* order   = w + o;           o += N_NODES;
  uint32_t* cursor2 = w + o;           o += CNT2W;
  uint2* wl0        = (uint2*)(w + o); o += 2*(size_t)WLCAP;
  uint2* wl1        = (uint2*)(w + o); o += 2*(size_t)WLCAP;
  uint32_t* kc      = w + o;           o += N_EDGES;
  uint32_t* dcnt    = w + o;           o += N_EDGES;
  uint32_t* bsums   = w + o;           o += 4096;
  float* psumS      = (float*)(w + o); o += PSUMW;
  float* dsum       = (float*)(w + o); o += (size_t)N_EDGES*FDIM;
  uint32_t* bitmap  = w + o;           o += wcap;
  uint32_t* wpref   = w + o;           o += wcap;

  const int EB  = (N_EDGES + 255)/256;
  const int WSB = (int)((wcap + 2047)/2048);           // <= 4096

  k_zero<<<128,256,0,stream>>>((uint4*)w, (uint32_t)(zero_words/4));
  // selection: 4 hist levels (prior digits recomputed in-block; L init fused in L1)
  k_hist8<1><<<HB,256,0,stream>>>(att, hists, labels);
  k_hist8<2><<<HB,256,0,stream>>>(att, hists, labels);
  k_hist8<3><<<HB,256,0,stream>>>(att, hists, labels);
  k_hist8<4><<<HB,256,0,stream>>>(att, hists, labels);
  // cooperative middle section: seed .. scatter
  {
    void* kargs[] = { (void*)&att, (void*)&src, (void*)&dst, (void*)&hists, (void*)&sc,
                      (void*)&tieIdx, (void*)&labels, (void*)&wl0, (void*)&wl1, (void*)&bsums,
                      (void*)&rank_, (void*)&cluster_i, (void*)&outC, (void*)&counts,
                      (void*)&counts2, (void*)&psumS, (void*)&bitmap, (void*)&cursor2,
                      (void*)&order };
    hipLaunchCooperativeKernel((void*)k_mega, dim3(CGB), dim3(256), kargs, 0, stream);
  }
  k_seg_edges<<<SGB + EB,256,0,stream>>>(primal_x, order, cluster_i, psumS,
                                         src, dst, sc, outE, kc, bitmap);
  k_scan_reduce1<<<WSB,256,0,stream>>>(bitmap, bsums, sc, dsum, dcnt);   // + lazy zero dsum/dcnt
  k_scan_apply1<<<WSB,256,0,stream>>>(bitmap, bsums, WSB, wpref, sc);    // -> wpref, SC_U
  k_dualacc<<<EB,256,0,stream>>>(dual_x, kc, bitmap, wpref, dsum, dcnt);
  k_finalize<<<2048,256,0,stream>>>((const float4*)psumS, counts, (const float4*)dsum,
                                    dcnt, sc, (float4*)out);
}

// Round 15
// 592.279 us; speedup vs baseline: 3.0239x; 3.0239x over previous
//
#include <hip/hip_runtime.h>
#include <stdint.h>

// DualPrimalEdgePooling on MI355X — 26 dispatches (coop mega-kernel REVERTED:
// grid.sync measured ~95us on MI355X, worse than dispatch boundaries).
// radix-select -> worklist min-label CC (jump fused via atomicMin, block-agg
// appends) -> flatten/rank scan -> cluster/counts -> 16-shadow counting-sort
// scatter -> 64-rows/wave shfl-broadcast segmented mean into 8 shadow
// accumulators (fused with edges+bitmap) -> popcount-prefix dual ranking ->
// finalize streams the full output.

#define N_NODES 200000
#define N_EDGES 600000
#define FDIM 128
#define NUM_POOL 300000u  // = E - NUM_KEEP

#define SC_NEEDEQ 3
#define SC_TIECNT 4
#define SC_C 5
#define SC_W 6
#define SC_U 7
#define SC_VCNT 8
#define SC_WL0 16        // per-round worklist counters: slots 16..24 (never reset)
#define TIECAP 4096
#define WLCAP 300800
#define HB 256           // hist grid blocks
#define NSB 98           // ceil(N/2048)
#define NSHAD 8          // psum shadow copies (atomic-depth divider)
#define NSHAD2 16        // scatter cursor shadows
#define CMAX 16384       // max clusters supported (bitmap/pair-key bound)
#define SROWS 64         // rows per wave in segsum (64: 3126 waves for TLP)
#define SGB 782          // ceil(N/(SROWS*4)) segsum blocks
#define CS2B 128         // scan blocks for counts2 (CMAX*16/2048)

__device__ __forceinline__ uint32_t f2ou(float f){
  uint32_t b = __float_as_uint(f);
  return (b & 0x80000000u) ? ~b : (b | 0x80000000u);
}

// block-wide digit selection from a completed 256-bin histogram (blockDim=256)
static __device__ __forceinline__ void sel_level(const uint32_t* hist, uint32_t& target,
                                                 uint32_t& pfx, uint32_t* sm, uint32_t* res){
  int t = threadIdx.x;
  uint32_t cnt = hist[t];
  sm[t] = cnt; __syncthreads();
  for(int off = 1; off < 256; off <<= 1){
    uint32_t y = (t + off < 256) ? sm[t + off] : 0u;
    __syncthreads(); sm[t] += y; __syncthreads();
  }
  uint32_t suffix = sm[t];            // candidates with digit >= t
  uint32_t above  = suffix - cnt;
  if(above < target && target <= suffix){ res[0] = (uint32_t)t; res[1] = target - above; }
  __syncthreads();
  pfx = (pfx << 8) | res[0];
  target = res[1];
  __syncthreads();
}

// block-wide exclusive scan of one value per thread (blockDim=256); ends synced
static __device__ __forceinline__ uint32_t blk_excl(uint32_t v, uint32_t* sm, uint32_t& total){
  int t = threadIdx.x;
  sm[t] = v; __syncthreads();
  for(int off = 1; off < 256; off <<= 1){
    uint32_t y = (t >= off) ? sm[t - off] : 0u;
    __syncthreads(); sm[t] += y; __syncthreads();
  }
  total = sm[255];
  uint32_t incl = sm[t];
  __syncthreads();
  return incl - v;
}

// ---- tiny ws zero (sc + hists only; counts/counts2 zeroed in k_seed) ----
__global__ __launch_bounds__(256) void k_zero(uint4* w4, uint32_t n4){
  uint32_t gid = blockIdx.x*256 + threadIdx.x;
  uint4 z = make_uint4(0u,0u,0u,0u);
  for(uint32_t j = gid; j < n4; j += gridDim.x*256) w4[j] = z;
}

// ---- selection: 4-level 8-bit radix histograms; prior-level digits recomputed in-block ----
template<int LEVEL>
__global__ __launch_bounds__(256) void k_hist8(const float* att, uint32_t* hists, int* L){
  __shared__ uint32_t h[256];
  __shared__ uint32_t sm[256];
  __shared__ uint32_t res[2];
  h[threadIdx.x] = 0;
  if(LEVEL == 1){
    for(int i = blockIdx.x*256 + threadIdx.x; i < N_NODES; i += HB*256) L[i] = i;  // fused CC init
  }
  __syncthreads();
  uint32_t pfx = 0, target = NUM_POOL;
  #pragma unroll
  for(int l = 0; l < LEVEL-1; ++l) sel_level(hists + 256*l, target, pfx, sm, res);
  constexpr int SH1 = (LEVEL > 1) ? 8*(5-LEVEL) : 0;
  constexpr int SH2 = 8*(4-LEVEL);
  for(int e = blockIdx.x*256 + threadIdx.x; e < N_EDGES; e += HB*256){
    uint32_t u = f2ou(att[e]);
    bool ok = (LEVEL == 1) || ((u >> SH1) == pfx);
    if(ok) atomicAdd(&h[(u >> SH2) & 0xFFu], 1u);
  }
  __syncthreads();
  uint32_t c = h[threadIdx.x];
  if(c) atomicAdd(&hists[256*(LEVEL-1) + threadIdx.x], c);
}

// ---- seed: zero counts/counts2 (first use is 5 dispatches later); recompute threshold
//      in-block; pooled edges hook + block-agg worklist append; ties recorded ----
__global__ __launch_bounds__(256) void k_seed(const float* att, const int* src, const int* dst,
                       const uint32_t* hists, uint32_t* sc, uint32_t* tieIdx, int* L, uint2* wl,
                       uint32_t* counts, uint32_t* counts2){
  __shared__ uint32_t sm[256];
  __shared__ uint32_t res[2];
  __shared__ uint32_t basesh;
  {
    uint32_t gid = blockIdx.x*256 + threadIdx.x;
    uint32_t gs = gridDim.x*256;
    const uint32_t TOTZ = N_NODES + CMAX*NSHAD2;
    for(uint32_t j = gid; j < TOTZ; j += gs){
      if(j < N_NODES) counts[j] = 0u; else counts2[j - N_NODES] = 0u;
    }
  }
  uint32_t pfx = 0, target = NUM_POOL;
  #pragma unroll
  for(int l = 0; l < 4; ++l) sel_level(hists + 256*l, target, pfx, sm, res);
  if(blockIdx.x == 0 && threadIdx.x == 0) sc[SC_NEEDEQ] = target;
  uint32_t T = pfx;
  int e = blockIdx.x*256 + threadIdx.x;
  bool app = false; int u = 0, v = 0;
  if(e < N_EDGES){
    uint32_t ub = f2ou(att[e]);
    if(ub > T){
      u = src[e]; v = dst[e];
      if(u != v){
        int m = u < v ? u : v, hi = u ^ v ^ m;
        atomicMin(&L[hi], m);
        app = true;
      }
    } else if(ub == T){
      uint32_t p = atomicAdd(&sc[SC_TIECNT], 1u);
      if(p < TIECAP) tieIdx[p] = (uint32_t)e;
    }
  }
  uint32_t tot;
  uint32_t off = blk_excl(app ? 1u : 0u, sm, tot);
  if(threadIdx.x == 0 && tot) basesh = atomicAdd(&sc[SC_WL0], tot);
  __syncthreads();
  if(app) wl[basesh + off] = make_uint2((uint32_t)(u < v ? u : v), (uint32_t)(u > v ? u : v));
}
__global__ __launch_bounds__(1024) void k_tiesel(uint32_t* sc, const uint32_t* tieIdx,
                        const int* src, const int* dst, int* L, uint2* wl){
  uint32_t m = sc[SC_TIECNT]; if(m > TIECAP) m = TIECAP;
  uint32_t need = sc[SC_NEEDEQ];
  int lane = threadIdx.x & 63;
  for(uint32_t i0 = 0; i0 < m; i0 += 1024){
    uint32_t i = i0 + threadIdx.x;
    bool app = false; int u = 0, v = 0;
    if(i < m){
      uint32_t mine = tieIdx[i];
      uint32_t r = 0;
      for(uint32_t j = 0; j < m; j++) r += (tieIdx[j] < mine) ? 1u : 0u;
      if(r < need){   // stable argsort: smallest indices pooled
        u = src[mine]; v = dst[mine];
        if(u != v){ int mm = u < v ? u : v, hi = u ^ v ^ mm; atomicMin(&L[hi], mm); app = true; }
      }
    }
    unsigned long long grp = __ballot(app);
    if(grp){
      int leader = __ffsll(grp) - 1;
      uint32_t base = 0;
      if(lane == leader) base = atomicAdd(&sc[SC_WL0], (uint32_t)__popcll(grp));
      base = (uint32_t)__shfl((int)base, leader);
      if(app){
        uint32_t off = (uint32_t)__popcll(grp & ((1ull << lane) - 1ull));
        wl[base + off] = make_uint2((uint32_t)(u < v ? u : v), (uint32_t)(u > v ? u : v));
      }
    }
  }
}
// relax + fused pointer jump: 4-level chase (plain loads), one-shot hooking atomicMin,
// survivors re-appended via block-agg. Jump slice uses ATOMICMIN (not plain store):
// concurrent hooks from other blocks can never be lost (monotone decrease only).
__global__ __launch_bounds__(256) void k_relax(const uint2* wl_in, uint2* wl_out, int* L,
                       uint32_t* sc, int inSlot, int outSlot){
  __shared__ uint32_t sm[256];
  __shared__ uint32_t basesh;
  uint32_t n = sc[inSlot];
  for(uint32_t base = blockIdx.x*256u; base < n; base += gridDim.x*256u){
    uint32_t idx = base + threadIdx.x;
    bool active = idx < n;
    int lu = 0, lv = 0;
    if(active){
      uint2 ed = wl_in[idx];
      lu = L[ed.x]; lu = L[lu]; lu = L[lu]; lu = L[lu];
      lv = L[ed.y]; lv = L[lv]; lv = L[lv]; lv = L[lv];
      active = (lu != lv);
      if(active){
        int m = lu < lv ? lu : lv, hi = lu ^ lv ^ m;
        atomicMin(&L[hi], m);
      }
    }
    uint32_t tot;
    uint32_t off = blk_excl(active ? 1u : 0u, sm, tot);
    if(threadIdx.x == 0 && tot) basesh = atomicAdd(&sc[outSlot], tot);
    __syncthreads();
    if(active) wl_out[basesh + off] = make_uint2((uint32_t)(lu < lv ? lu : lv),
                                                 (uint32_t)(lu > lv ? lu : lv));
    __syncthreads();
  }
  if(n != 0){   // fused jump slice: monotone atomicMin => race-free vs concurrent hooks
    int i = blockIdx.x*256 + threadIdx.x;
    if(i < N_NODES){
      int v = L[i]; v = L[v]; v = L[v]; v = L[v];
      if(v < i) atomicMin(&L[i], v);
    }
  }
}
// flatten to roots + per-block root-count reduction (2048 nodes/block)
__global__ __launch_bounds__(256) void k_flatten_reduce(int* L, uint32_t* bsums){
  uint32_t base = blockIdx.x*2048u + threadIdx.x*8u;
  uint32_t s = 0;
  #pragma unroll
  for(int k = 0; k < 8; k++){
    uint32_t i = base + k;
    if(i < N_NODES){
      int p = L[i]; int q = L[p];
      while(q != p){ p = q; q = L[p]; }
      L[i] = p;
      s += (p == (int)i) ? 1u : 0u;
    }
  }
  __shared__ uint32_t sm[256];
  sm[threadIdx.x] = s; __syncthreads();
  for(int off = 128; off > 0; off >>= 1){
    if((int)threadIdx.x < off) sm[threadIdx.x] += sm[threadIdx.x + off];
    __syncthreads();
  }
  if(threadIdx.x == 0) bsums[blockIdx.x] = sm[0];
}

// ---- 2-kernel scans. MODE 1: popc(bitmap)->wpref (+SC_U). MODE 2: rootflag(L)->rank_
//      (+SC_C,SC_W). MODE 3: counts2->cursor2 (n = C*NSHAD2). apply scans bsums in-LDS. ----
template<int MODE>
__device__ __forceinline__ uint32_t scan_n(const uint32_t* sc){
  if(MODE == 1) return sc[SC_W];
  if(MODE == 3) return sc[SC_C]*NSHAD2;
  return N_NODES;
}
template<int MODE>
__global__ __launch_bounds__(256) void k_scan_reduce(const uint32_t* in, uint32_t* bsums,
                       const uint32_t* sc, float* dsum, uint32_t* dcnt){
  uint32_t n = scan_n<MODE>(sc);
  if(MODE == 1){  // lazy-zero compact dual accumulators (VCNT rows >= U), vectorized
    uint32_t vc = sc[SC_VCNT];
    size_t gid = (size_t)blockIdx.x*256 + threadIdx.x, gs = (size_t)gridDim.x*256;
    float4* d4 = (float4*)dsum;
    float4 z = make_float4(0.f,0.f,0.f,0.f);
    for(size_t j = gid; j < (size_t)vc*(FDIM/4); j += gs) d4[j] = z;
    for(size_t j = gid; j < vc; j += gs) dcnt[j] = 0u;
  }
  uint32_t base = blockIdx.x*2048u + threadIdx.x*8u;
  uint32_t s = 0;
  #pragma unroll
  for(int k = 0; k < 8; k++){
    uint32_t idx = base + k;
    if(idx < n){ uint32_t v = in[idx]; if(MODE == 1) v = __popc(v); s += v; }
  }
  __shared__ uint32_t sm[256];
  sm[threadIdx.x] = s; __syncthreads();
  for(int off = 128; off > 0; off >>= 1){
    if((int)threadIdx.x < off) sm[threadIdx.x] += sm[threadIdx.x + off];
    __syncthreads();
  }
  if(threadIdx.x == 0) bsums[blockIdx.x] = sm[0];
}
template<int MODE>
__global__ __launch_bounds__(256) void k_scan_apply(const uint32_t* in, const int* L,
                       const uint32_t* bsums, int nb, uint32_t* out, uint32_t* sc){
  __shared__ uint32_t bs[4096];
  __shared__ uint32_t sm[256];
  int t = threadIdx.x;
  uint32_t n = scan_n<MODE>(sc);
  uint32_t loc[16]; uint32_t ls = 0;
  #pragma unroll
  for(int k = 0; k < 16; k++){ int idx = t*16 + k; uint32_t v = (idx < nb) ? bsums[idx] : 0u; loc[k] = v; ls += v; }
  sm[t] = ls; __syncthreads();
  for(int off = 1; off < 256; off <<= 1){
    uint32_t y = (t >= off) ? sm[t - off] : 0u;
    __syncthreads(); sm[t] += y; __syncthreads();
  }
  uint32_t total = sm[255];
  uint32_t run = sm[t] - ls;
  #pragma unroll
  for(int k = 0; k < 16; k++){ bs[t*16 + k] = run; run += loc[k]; }
  __syncthreads();
  uint32_t blockbase = bs[blockIdx.x];
  __syncthreads();
  uint32_t base = blockIdx.x*2048u + t*8u;
  uint32_t xs[8]; uint32_t ts2 = 0;
  #pragma unroll
  for(int k = 0; k < 8; k++){
    uint32_t idx = base + k; uint32_t v = 0;
    if(idx < n){
      if(MODE == 2) v = (L[idx] == (int)idx) ? 1u : 0u;
      else { v = in[idx]; if(MODE == 1) v = __popc(v); }
    }
    xs[k] = v; ts2 += v;
  }
  sm[t] = ts2; __syncthreads();
  for(int off = 1; off < 256; off <<= 1){
    uint32_t y = (t >= off) ? sm[t - off] : 0u;
    __syncthreads(); sm[t] += y; __syncthreads();
  }
  uint32_t run2 = blockbase + sm[t] - ts2;
  #pragma unroll
  for(int k = 0; k < 8; k++){ uint32_t idx = base + k; if(idx < n) out[idx] = run2; run2 += xs[k]; }
  if(blockIdx.x == 0 && t == 0){
    if(MODE == 2){ sc[SC_C] = total; uint64_t cc = (uint64_t)total*(uint64_t)total; sc[SC_W] = (uint32_t)((cc + 31ull) >> 5); }
    if(MODE == 1){ sc[SC_U] = total; }
  }
}

// ---- cluster ids + wave-agg counts (total + per-shadow) + lazy zero psumS/bitmap ----
__global__ __launch_bounds__(256) void k_cluster_counts(const int* L, const uint32_t* rank_,
                       int* cluster_i, float* outC, uint32_t* counts, uint32_t* counts2,
                       float* psumS, uint32_t* bitmap, const uint32_t* sc){
  uint32_t C = sc[SC_C], W = sc[SC_W];
  uint32_t gid = blockIdx.x*256 + threadIdx.x, gs = gridDim.x*256;
  float4* p4 = (float4*)psumS;
  float4 z = make_float4(0.f,0.f,0.f,0.f);
  for(size_t j = gid; j < (size_t)NSHAD*C*(FDIM/4); j += gs) p4[j] = z;
  for(uint32_t j = gid; j < W; j += gs) bitmap[j] = 0u;
  int i = (int)gid;
  int lane = threadIdx.x & 63;
  int sh = (int)((gid >> 6) & (NSHAD2-1));
  int c = -1;
  if(i < N_NODES){
    c = (int)rank_[L[i]];
    cluster_i[i] = c;
    outC[i] = (float)c;
  }
  unsigned long long remaining = __ballot(i < N_NODES);
  while(remaining){
    int leader = __ffsll(remaining) - 1;
    int lc = __shfl(c, leader);
    unsigned long long grp = __ballot(c == lc) & remaining;
    if(lane == leader){
      uint32_t cnt = (uint32_t)__popcll(grp);
      atomicAdd(&counts[lc], cnt);                       // fire-and-forget (means)
      atomicAdd(&counts2[lc*NSHAD2 + sh], cnt);          // per-shadow capacity
    }
    remaining &= ~grp;
  }
}
// scatter via 16-shadow cursors: same grid geometry as k_cluster_counts => exact capacities
__global__ void k_scatter(const int* cluster_i, uint32_t* cursor2, uint32_t* order){
  uint32_t gid = blockIdx.x*256 + threadIdx.x;
  int i = (int)gid;
  int lane = threadIdx.x & 63;
  int sh = (int)((gid >> 6) & (NSHAD2-1));
  int c = (i < N_NODES) ? cluster_i[i] : -1;
  unsigned long long remaining = __ballot(i < N_NODES);
  while(remaining){
    int leader = __ffsll(remaining) - 1;
    int lc = __shfl(c, leader);
    unsigned long long grp = __ballot(c == lc) & remaining;
    int b = 0;
    if(lane == leader) b = (int)atomicAdd(&cursor2[lc*NSHAD2 + sh], (uint32_t)__popcll(grp));
    b = __shfl(b, leader);
    if((grp >> lane) & 1ull){
      uint32_t sub = (uint32_t)__popcll(grp & ((1ull << lane) - 1ull));
      order[(uint32_t)b + sub] = (uint32_t)i;
    }
    remaining &= ~grp;
  }
}

// ---- fused: segmented mean into 8-shadow psum (blocks < SGB; 64 rows/wave) |
//      edges+bitmap (rest) ----
__global__ __launch_bounds__(256) void k_seg_edges(const float* px, const uint32_t* order,
        const int* cluster_i, float* psumS, const int* src, const int* dst, uint32_t* sc,
        float* outE, uint32_t* kc, uint32_t* bitmap){
  if(blockIdx.x < SGB){
    int wave = (int)((blockIdx.x*256u + threadIdx.x) >> 6);
    int lane = threadIdx.x & 63;
    int start = wave * SROWS;
    if(start >= N_NODES) return;
    int cnt = N_NODES - start; if(cnt > SROWS) cnt = SROWS;
    size_t shadBase = (size_t)(wave & (NSHAD-1)) * (size_t)sc[SC_C] * FDIM;
    uint32_t ord0 = 0; int c0 = -1;
    if(lane < cnt){ ord0 = order[start + lane]; c0 = cluster_i[ord0]; }
    float ax = 0.f, ay = 0.f; int cur = -1;
    for(int r = 0; r < cnt; r++){
      uint32_t i = (uint32_t)__shfl((int)ord0, r);
      int c = __shfl(c0, r);
      if(c != cur){
        if(cur >= 0){
          atomicAdd(&psumS[shadBase + (size_t)cur*FDIM + 2*lane], ax);
          atomicAdd(&psumS[shadBase + (size_t)cur*FDIM + 2*lane + 1], ay);
        }
        cur = c; ax = 0.f; ay = 0.f;
      }
      float2 v = ((const float2*)(px + (size_t)i*FDIM))[lane];
      ax += v.x; ay += v.y;
    }
    if(cur >= 0){
      atomicAdd(&psumS[shadBase + (size_t)cur*FDIM + 2*lane], ax);
      atomicAdd(&psumS[shadBase + (size_t)cur*FDIM + 2*lane + 1], ay);
    }
  } else {
    __shared__ uint32_t wsum[4];
    int e = (blockIdx.x - SGB)*256 + threadIdx.x;
    int lane = threadIdx.x & 63;
    int wv = threadIdx.x >> 6;
    bool val = false;
    if(e < N_EDGES){
      int cu = cluster_i[src[e]];
      int cv = cluster_i[dst[e]];
      val = (cu != cv);
      outE[e] = val ? (float)cu : -1.0f;
      outE[N_EDGES + e] = val ? (float)cv : -1.0f;
      if(val){
        int a = cu < cv ? cu : cv, b = cu < cv ? cv : cu;
        uint32_t C = sc[SC_C];
        uint32_t key = (uint32_t)a * C + (uint32_t)b;
        kc[e] = key;
        atomicOr(&bitmap[key >> 5], 1u << (key & 31u));
      } else {
        kc[e] = 0xFFFFFFFFu;
      }
    }
    unsigned long long grp = __ballot(val);
    if(lane == 0) wsum[wv] = (uint32_t)__popcll(grp);
    __syncthreads();
    if(threadIdx.x == 0){
      uint32_t s = wsum[0] + wsum[1] + wsum[2] + wsum[3];
      if(s) atomicAdd(&sc[SC_VCNT], s);   // fire-and-forget (upper bound for dsum zeroing)
    }
  }
}

// ---- dual accumulate: 64 edges/wave, ballot + shfl-broadcast rank ----
__global__ __launch_bounds__(256) void k_dualacc(const float* dx, const uint32_t* kc,
                          const uint32_t* bitmap, const uint32_t* wpref,
                          float* dsum, uint32_t* dcnt){
  int wave = (int)((blockIdx.x*256u + threadIdx.x) >> 6);
  int lane = threadIdx.x & 63;
  int base = wave * 64;
  if(base >= N_EDGES) return;
  int e = base + lane;
  uint32_t key = (e < N_EDGES) ? kc[e] : 0xFFFFFFFFu;
  bool val = (key != 0xFFFFFFFFu);
  uint32_t r = 0;
  if(val){
    uint32_t wi = key >> 5, bi = key & 31u;
    r = wpref[wi] + __popc(bitmap[wi] & ((1u << bi) - 1u));
  }
  unsigned long long m = __ballot(val);
  while(m){
    int b = __ffsll(m) - 1;
    m &= m - 1;
    uint32_t ee = (uint32_t)(base + b);
    uint32_t rr = (uint32_t)__shfl((int)r, b);
    float2 v = ((const float2*)(dx + (size_t)ee*FDIM))[lane];
    atomicAdd(&dsum[(size_t)rr*FDIM + 2*lane], v.x);
    atomicAdd(&dsum[(size_t)rr*FDIM + 2*lane + 1], v.y);
    if(lane == 0) atomicAdd(&dcnt[rr], 1u);
  }
}
// ---- stream the full output region: shadow-summed means for live rows, zeros elsewhere ----
__global__ __launch_bounds__(256) void k_finalize(const float4* psumS, const uint32_t* counts,
        const float4* dsum, const uint32_t* dcnt, const uint32_t* sc, float4* out4){
  uint32_t C = sc[SC_C], U = sc[SC_U];
  size_t cs = (size_t)C * (FDIM/4);          // shadow stride in float4
  size_t gid = (size_t)blockIdx.x*256 + threadIdx.x;
  size_t gs = (size_t)gridDim.x*256;
  const size_t NP4 = (size_t)N_NODES*(FDIM/4);
  const size_t TOT4 = (size_t)(N_NODES + N_EDGES)*(FDIM/4);
  for(size_t j = gid; j < TOT4; j += gs){
    float4 v = make_float4(0.f,0.f,0.f,0.f);
    if(j < NP4){
      uint32_t r = (uint32_t)(j >> 5);
      if(r < C){
        v = psumS[j];
        #pragma unroll
        for(int s = 1; s < NSHAD; s++){
          float4 t = psumS[(size_t)s*cs + j];
          v.x += t.x; v.y += t.y; v.z += t.z; v.w += t.w;
        }
        float fc = (float)counts[r];
        v.x /= fc; v.y /= fc; v.z /= fc; v.w /= fc;
      }
    } else {
      size_t dj = j - NP4;
      uint32_t r = (uint32_t)(dj >> 5);
      if(r < U){
        v = dsum[dj];
        float fc = (float)dcnt[r];
        v.x /= fc; v.y /= fc; v.z /= fc; v.w /= fc;
      }
    }
    out4[j] = v;
  }
}

extern "C" void kernel_launch(void* const* d_in, const int* in_sizes, int n_in,
                              void* d_out, int out_size, void* d_ws, size_t ws_size,
                              hipStream_t stream){
  (void)in_sizes; (void)n_in; (void)out_size;
  const float* primal_x = (const float*)d_in[0];
  const float* dual_x   = (const float*)d_in[1];
  const float* att      = (const float*)d_in[2];
  const int*   pei      = (const int*)d_in[3];
  const int* src = pei;
  const int* dst = pei + N_EDGES;

  float* out  = (float*)d_out;
  float* outE = out + (size_t)(N_NODES + N_EDGES)*FDIM;   // (2, E)
  float* outC = outE + (size_t)2*N_EDGES;                 // (N,)

  uint32_t* w = (uint32_t*)d_ws;
  size_t words_avail = ws_size / 4;
  const size_t PSUMW = (size_t)NSHAD*CMAX*FDIM;            // 16.8M words
  const size_t CNT2W = (size_t)CMAX*NSHAD2;                // 262144 words
  const size_t FIXED = 64 + 1024 + (size_t)N_NODES + CNT2W
                     + TIECAP + 4*(size_t)N_NODES + CNT2W + 4*(size_t)WLCAP
                     + (size_t)N_EDGES + (size_t)N_EDGES   // kc + dcnt
                     + 4096
                     + PSUMW + (size_t)N_EDGES*FDIM;       // psumS + dsum
  size_t wcap = (words_avail > FIXED) ? (words_avail - FIXED)/2 : 4;
  if(wcap > 8388608) wcap = 8388608;   // supports C up to 16384
  wcap &= ~(size_t)3;

  size_t o = 0;
  uint32_t* sc      = w;               o += 64;
  uint32_t* hists   = w + o;           o += 1024;          // 4 x 256
  size_t zero_words = o;                                    // zeroed per call (1088, mult of 4)
  uint32_t* counts  = w + o;           o += N_NODES;       // zeroed in k_seed
  uint32_t* counts2 = w + o;           o += CNT2W;         // zeroed in k_seed
  uint32_t* tieIdx  = w + o;           o += TIECAP;
  int* labels       = (int*)(w + o);   o += N_NODES;
  uint32_t* rank_   = w + o;           o += N_NODES;
  int* cluster_i    = (int*)(w + o);   o += N_NODES;
  uint32_t* order   = w + o;           o += N_NODES;
  uint32_t* cursor2 = w + o;           o += CNT2W;
  uint2* wl0        = (uint2*)(w + o); o += 2*(size_t)WLCAP;
  uint2* wl1        = (uint2*)(w + o); o += 2*(size_t)WLCAP;
  uint32_t* kc      = w + o;           o += N_EDGES;
  uint32_t* dcnt    = w + o;           o += N_EDGES;
  uint32_t* bsums   = w + o;           o += 4096;
  float* psumS      = (float*)(w + o); o += PSUMW;
  float* dsum       = (float*)(w + o); o += (size_t)N_EDGES*FDIM;
  uint32_t* bitmap  = w + o;           o += wcap;
  uint32_t* wpref   = w + o;           o += wcap;

  const int EB  = (N_EDGES + 255)/256;
  const int NB  = (N_NODES + 255)/256;
  const int WSB = (int)((wcap + 2047)/2048);           // <= 4096

  k_zero<<<2,256,0,stream>>>((uint4*)w, (uint32_t)(zero_words/4));
  // selection: 4 hist levels (prior digits recomputed in-block; L init fused in L1)
  k_hist8<1><<<HB,256,0,stream>>>(att, hists, labels);
  k_hist8<2><<<HB,256,0,stream>>>(att, hists, labels);
  k_hist8<3><<<HB,256,0,stream>>>(att, hists, labels);
  k_hist8<4><<<HB,256,0,stream>>>(att, hists, labels);
  // CC: seed (+counts/counts2 zero) + tie handling + relax ladder (jump fused via atomicMin)
  k_seed<<<EB,256,0,stream>>>(att, src, dst, hists, sc, tieIdx, labels, wl0, counts, counts2);
  k_tiesel<<<1,1024,0,stream>>>(sc, tieIdx, src, dst, labels, wl0);
  for(int r = 1; r <= 8; ++r){
    uint2* win  = (r & 1) ? wl0 : wl1;
    uint2* wout = (r & 1) ? wl1 : wl0;
    k_relax<<<1024,256,0,stream>>>(win, wout, labels, sc, SC_WL0 + r - 1, SC_WL0 + r);
  }
  k_flatten_reduce<<<NSB,256,0,stream>>>(labels, bsums);
  k_scan_apply<2><<<NSB,256,0,stream>>>(counts, labels, bsums, NSB, rank_, sc);   // -> rank_, SC_C, SC_W
  k_cluster_counts<<<NB,256,0,stream>>>(labels, rank_, cluster_i, outC, counts, counts2,
                                        psumS, bitmap, sc);
  k_scan_reduce<3><<<CS2B,256,0,stream>>>(counts2, bsums, sc, dsum, dcnt);
  k_scan_apply<3><<<CS2B,256,0,stream>>>(counts2, labels, bsums, CS2B, cursor2, sc); // -> cursor2
  k_scatter<<<NB,256,0,stream>>>(cluster_i, cursor2, order);
  k_seg_edges<<<SGB + EB,256,0,stream>>>(primal_x, order, cluster_i, psumS,
                                         src, dst, sc, outE, kc, bitmap);
  k_scan_reduce<1><<<WSB,256,0,stream>>>(bitmap, bsums, sc, dsum, dcnt);          // + lazy zero dsum/dcnt
  k_scan_apply<1><<<WSB,256,0,stream>>>(bitmap, labels, bsums, WSB, wpref, sc);   // -> wpref, SC_U
  k_dualacc<<<EB,256,0,stream>>>(dual_x, kc, bitmap, wpref, dsum, dcnt);
  k_finalize<<<2048,256,0,stream>>>((const float4*)psumS, counts, (const float4*)dsum,
                                    dcnt, sc, (float4*)out);
}

// Round 16
// 589.775 us; speedup vs baseline: 3.0367x; 1.0042x over previous
//
#include <hip/hip_runtime.h>
#include <stdint.h>

// DualPrimalEdgePooling on MI355X — 24 dispatches.
// 3-level radix-select (24-bit prefix; full-key tie ranking fused into relax
// round 1) -> worklist min-label CC (jump fused via atomicMin, block-agg
// appends) -> flatten/rank scan -> cluster/counts -> 16-shadow counting-sort
// scatter -> 64-rows/wave shfl-broadcast segmented mean into 4 shadow
// accumulators (fused with edges+bitmap) -> popcount-prefix dual ranking ->
// finalize streams the full output.
// NOTE: cooperative grid.sync measured ~95us/sync on MI355X — never mega-kernel.

#define N_NODES 200000
#define N_EDGES 600000
#define FDIM 128
#define NUM_POOL 300000u  // = E - NUM_KEEP

#define SC_NEEDEQ 3
#define SC_TIECNT 4
#define SC_C 5
#define SC_W 6
#define SC_U 7
#define SC_VCNT 8
#define SC_WL0 16        // per-round worklist counters: slots 16..24 (never reset)
#define TIECAP 4096
#define WLCAP 300800
#define HB 256           // hist grid blocks
#define NSB 98           // ceil(N/2048)
#define NSHAD 4          // psum shadow copies (atomic-depth divider)
#define NSHAD2 16        // scatter cursor shadows
#define CMAX 16384       // max clusters supported (bitmap/pair-key bound)
#define SROWS 64         // rows per wave in segsum (3126 waves for TLP)
#define SGB 782          // ceil(N/(SROWS*4)) segsum blocks
#define CS2B 128         // scan blocks for counts2 (CMAX*16/2048)

__device__ __forceinline__ uint32_t f2ou(float f){
  uint32_t b = __float_as_uint(f);
  return (b & 0x80000000u) ? ~b : (b | 0x80000000u);
}

// block-wide digit selection from a completed 256-bin histogram (blockDim=256)
static __device__ __forceinline__ void sel_level(const uint32_t* hist, uint32_t& target,
                                                 uint32_t& pfx, uint32_t* sm, uint32_t* res){
  int t = threadIdx.x;
  uint32_t cnt = hist[t];
  sm[t] = cnt; __syncthreads();
  for(int off = 1; off < 256; off <<= 1){
    uint32_t y = (t + off < 256) ? sm[t + off] : 0u;
    __syncthreads(); sm[t] += y; __syncthreads();
  }
  uint32_t suffix = sm[t];            // candidates with digit >= t
  uint32_t above  = suffix - cnt;
  if(above < target && target <= suffix){ res[0] = (uint32_t)t; res[1] = target - above; }
  __syncthreads();
  pfx = (pfx << 8) | res[0];
  target = res[1];
  __syncthreads();
}

// block-wide exclusive scan of one value per thread (blockDim=256); ends synced
static __device__ __forceinline__ uint32_t blk_excl(uint32_t v, uint32_t* sm, uint32_t& total){
  int t = threadIdx.x;
  sm[t] = v; __syncthreads();
  for(int off = 1; off < 256; off <<= 1){
    uint32_t y = (t >= off) ? sm[t - off] : 0u;
    __syncthreads(); sm[t] += y; __syncthreads();
  }
  total = sm[255];
  uint32_t incl = sm[t];
  __syncthreads();
  return incl - v;
}

// ---- tiny ws zero (sc + hists only; counts/counts2 zeroed in k_seed) ----
__global__ __launch_bounds__(256) void k_zero(uint4* w4, uint32_t n4){
  uint32_t gid = blockIdx.x*256 + threadIdx.x;
  uint4 z = make_uint4(0u,0u,0u,0u);
  for(uint32_t j = gid; j < n4; j += gridDim.x*256) w4[j] = z;
}

// ---- selection: 3-level 8-bit radix histograms (24-bit prefix); prior digits
//      recomputed in-block ----
template<int LEVEL>
__global__ __launch_bounds__(256) void k_hist8(const float* att, uint32_t* hists, int* L){
  __shared__ uint32_t h[256];
  __shared__ uint32_t sm[256];
  __shared__ uint32_t res[2];
  h[threadIdx.x] = 0;
  if(LEVEL == 1){
    for(int i = blockIdx.x*256 + threadIdx.x; i < N_NODES; i += HB*256) L[i] = i;  // fused CC init
  }
  __syncthreads();
  uint32_t pfx = 0, target = NUM_POOL;
  #pragma unroll
  for(int l = 0; l < LEVEL-1; ++l) sel_level(hists + 256*l, target, pfx, sm, res);
  constexpr int SH1 = (LEVEL > 1) ? 8*(5-LEVEL) : 0;
  constexpr int SH2 = 8*(4-LEVEL);
  for(int e = blockIdx.x*256 + threadIdx.x; e < N_EDGES; e += HB*256){
    uint32_t u = f2ou(att[e]);
    bool ok = (LEVEL == 1) || ((u >> SH1) == pfx);
    if(ok) atomicAdd(&h[(u >> SH2) & 0xFFu], 1u);
  }
  __syncthreads();
  uint32_t c = h[threadIdx.x];
  if(c) atomicAdd(&hists[256*(LEVEL-1) + threadIdx.x], c);
}

// ---- seed: zero counts/counts2; recompute 24-bit threshold in-block; pooled edges
//      ((u>>8) > T) hook + block-agg worklist append; prefix-tie edges recorded ----
__global__ __launch_bounds__(256) void k_seed(const float* att, const int* src, const int* dst,
                       const uint32_t* hists, uint32_t* sc, uint32_t* tieIdx, int* L, uint2* wl,
                       uint32_t* counts, uint32_t* counts2){
  __shared__ uint32_t sm[256];
  __shared__ uint32_t res[2];
  __shared__ uint32_t basesh;
  {
    uint32_t gid = blockIdx.x*256 + threadIdx.x;
    uint32_t gs = gridDim.x*256;
    const uint32_t TOTZ = N_NODES + CMAX*NSHAD2;
    for(uint32_t j = gid; j < TOTZ; j += gs){
      if(j < N_NODES) counts[j] = 0u; else counts2[j - N_NODES] = 0u;
    }
  }
  uint32_t pfx = 0, target = NUM_POOL;
  #pragma unroll
  for(int l = 0; l < 3; ++l) sel_level(hists + 256*l, target, pfx, sm, res);
  if(blockIdx.x == 0 && threadIdx.x == 0) sc[SC_NEEDEQ] = target;
  uint32_t T = pfx;   // 24-bit prefix threshold
  int e = blockIdx.x*256 + threadIdx.x;
  bool app = false; int u = 0, v = 0;
  if(e < N_EDGES){
    uint32_t ub = f2ou(att[e]) >> 8;
    if(ub > T){
      u = src[e]; v = dst[e];
      if(u != v){
        int m = u < v ? u : v, hi = u ^ v ^ m;
        atomicMin(&L[hi], m);
        app = true;
      }
    } else if(ub == T){
      uint32_t p = atomicAdd(&sc[SC_TIECNT], 1u);
      if(p < TIECAP) tieIdx[p] = (uint32_t)e;
    }
  }
  uint32_t tot;
  uint32_t off = blk_excl(app ? 1u : 0u, sm, tot);
  if(threadIdx.x == 0 && tot) basesh = atomicAdd(&sc[SC_WL0], tot);
  __syncthreads();
  if(app) wl[basesh + off] = make_uint2((uint32_t)(u < v ? u : v), (uint32_t)(u > v ? u : v));
}

// relax + fused pointer jump + (round 1) fused tie selection.
// 4-level chase (plain loads), one-shot hooking atomicMin, survivors re-appended
// via block-agg. Jump slice uses ATOMICMIN: concurrent hooks never lost (monotone).
// Ties ranked by full ordered key DESC then index ASC (== stable argsort of -att);
// selected tie edges hook now and enter the round-2 worklist.
__global__ __launch_bounds__(256) void k_relax(const uint2* wl_in, uint2* wl_out, int* L,
                       uint32_t* sc, int inSlot, int outSlot,
                       const uint32_t* tieIdx, const float* att,
                       const int* src, const int* dst, int doTies){
  __shared__ uint32_t sm[256];
  __shared__ uint32_t basesh;
  uint32_t n = sc[inSlot];
  for(uint32_t base = blockIdx.x*256u; base < n; base += gridDim.x*256u){
    uint32_t idx = base + threadIdx.x;
    bool active = idx < n;
    int lu = 0, lv = 0;
    if(active){
      uint2 ed = wl_in[idx];
      lu = L[ed.x]; lu = L[lu]; lu = L[lu]; lu = L[lu];
      lv = L[ed.y]; lv = L[lv]; lv = L[lv]; lv = L[lv];
      active = (lu != lv);
      if(active){
        int m = lu < lv ? lu : lv, hi = lu ^ lv ^ m;
        atomicMin(&L[hi], m);
      }
    }
    uint32_t tot;
    uint32_t off = blk_excl(active ? 1u : 0u, sm, tot);
    if(threadIdx.x == 0 && tot) basesh = atomicAdd(&sc[outSlot], tot);
    __syncthreads();
    if(active) wl_out[basesh + off] = make_uint2((uint32_t)(lu < lv ? lu : lv),
                                                 (uint32_t)(lu > lv ? lu : lv));
    __syncthreads();
  }
  if(doTies && blockIdx.x == 0){
    uint32_t m = sc[SC_TIECNT]; if(m > TIECAP) m = TIECAP;
    uint32_t need = sc[SC_NEEDEQ];
    for(uint32_t i0 = 0; i0 < m; i0 += 256){
      uint32_t i = i0 + threadIdx.x;
      bool app = false; int u = 0, v = 0;
      if(i < m){
        uint32_t mine = tieIdx[i];
        uint32_t ki = f2ou(att[mine]);
        uint32_t r = 0;
        for(uint32_t j = 0; j < m; j++){
          uint32_t oj = tieIdx[j];
          uint32_t kj = f2ou(att[oj]);
          r += (kj > ki || (kj == ki && oj < mine)) ? 1u : 0u;
        }
        if(r < need){   // stable argsort of -att: higher att first, then smaller index
          u = src[mine]; v = dst[mine];
          if(u != v){ int mm = u < v ? u : v, hi = u ^ v ^ mm; atomicMin(&L[hi], mm); app = true; }
        }
      }
      uint32_t tot;
      uint32_t off = blk_excl(app ? 1u : 0u, sm, tot);
      if(threadIdx.x == 0 && tot) basesh = atomicAdd(&sc[outSlot], tot);
      __syncthreads();
      if(app) wl_out[basesh + off] = make_uint2((uint32_t)(u < v ? u : v),
                                                (uint32_t)(u > v ? u : v));
      __syncthreads();
    }
  }
  if(n != 0){   // fused jump slice: monotone atomicMin => race-free vs concurrent hooks
    int i = blockIdx.x*256 + threadIdx.x;
    if(i < N_NODES){
      int v = L[i]; v = L[v]; v = L[v]; v = L[v];
      if(v < i) atomicMin(&L[i], v);
    }
  }
}
// flatten to roots + per-block root-count reduction (2048 nodes/block)
__global__ __launch_bounds__(256) void k_flatten_reduce(int* L, uint32_t* bsums){
  uint32_t base = blockIdx.x*2048u + threadIdx.x*8u;
  uint32_t s = 0;
  #pragma unroll
  for(int k = 0; k < 8; k++){
    uint32_t i = base + k;
    if(i < N_NODES){
      int p = L[i]; int q = L[p];
      while(q != p){ p = q; q = L[p]; }
      L[i] = p;
      s += (p == (int)i) ? 1u : 0u;
    }
  }
  __shared__ uint32_t sm[256];
  sm[threadIdx.x] = s; __syncthreads();
  for(int off = 128; off > 0; off >>= 1){
    if((int)threadIdx.x < off) sm[threadIdx.x] += sm[threadIdx.x + off];
    __syncthreads();
  }
  if(threadIdx.x == 0) bsums[blockIdx.x] = sm[0];
}

// ---- 2-kernel scans. MODE 1: popc(bitmap)->wpref (+SC_U). MODE 2: rootflag(L)->rank_
//      (+SC_C,SC_W). MODE 3: counts2->cursor2 (n = C*NSHAD2). apply scans bsums in-LDS. ----
template<int MODE>
__device__ __forceinline__ uint32_t scan_n(const uint32_t* sc){
  if(MODE == 1) return sc[SC_W];
  if(MODE == 3) return sc[SC_C]*NSHAD2;
  return N_NODES;
}
template<int MODE>
__global__ __launch_bounds__(256) void k_scan_reduce(const uint32_t* in, uint32_t* bsums,
                       const uint32_t* sc, float* dsum, uint32_t* dcnt){
  uint32_t n = scan_n<MODE>(sc);
  if(MODE == 1){  // lazy-zero compact dual accumulators (VCNT rows >= U), vectorized
    uint32_t vc = sc[SC_VCNT];
    size_t gid = (size_t)blockIdx.x*256 + threadIdx.x, gs = (size_t)gridDim.x*256;
    float4* d4 = (float4*)dsum;
    float4 z = make_float4(0.f,0.f,0.f,0.f);
    for(size_t j = gid; j < (size_t)vc*(FDIM/4); j += gs) d4[j] = z;
    for(size_t j = gid; j < vc; j += gs) dcnt[j] = 0u;
  }
  uint32_t base = blockIdx.x*2048u + threadIdx.x*8u;
  uint32_t s = 0;
  #pragma unroll
  for(int k = 0; k < 8; k++){
    uint32_t idx = base + k;
    if(idx < n){ uint32_t v = in[idx]; if(MODE == 1) v = __popc(v); s += v; }
  }
  __shared__ uint32_t sm[256];
  sm[threadIdx.x] = s; __syncthreads();
  for(int off = 128; off > 0; off >>= 1){
    if((int)threadIdx.x < off) sm[threadIdx.x] += sm[threadIdx.x + off];
    __syncthreads();
  }
  if(threadIdx.x == 0) bsums[blockIdx.x] = sm[0];
}
template<int MODE>
__global__ __launch_bounds__(256) void k_scan_apply(const uint32_t* in, const int* L,
                       const uint32_t* bsums, int nb, uint32_t* out, uint32_t* sc){
  __shared__ uint32_t bs[4096];
  __shared__ uint32_t sm[256];
  int t = threadIdx.x;
  uint32_t n = scan_n<MODE>(sc);
  uint32_t loc[16]; uint32_t ls = 0;
  #pragma unroll
  for(int k = 0; k < 16; k++){ int idx = t*16 + k; uint32_t v = (idx < nb) ? bsums[idx] : 0u; loc[k] = v; ls += v; }
  sm[t] = ls; __syncthreads();
  for(int off = 1; off < 256; off <<= 1){
    uint32_t y = (t >= off) ? sm[t - off] : 0u;
    __syncthreads(); sm[t] += y; __syncthreads();
  }
  uint32_t total = sm[255];
  uint32_t run = sm[t] - ls;
  #pragma unroll
  for(int k = 0; k < 16; k++){ bs[t*16 + k] = run; run += loc[k]; }
  __syncthreads();
  uint32_t blockbase = bs[blockIdx.x];
  __syncthreads();
  uint32_t base = blockIdx.x*2048u + t*8u;
  uint32_t xs[8]; uint32_t ts2 = 0;
  #pragma unroll
  for(int k = 0; k < 8; k++){
    uint32_t idx = base + k; uint32_t v = 0;
    if(idx < n){
      if(MODE == 2) v = (L[idx] == (int)idx) ? 1u : 0u;
      else { v = in[idx]; if(MODE == 1) v = __popc(v); }
    }
    xs[k] = v; ts2 += v;
  }
  sm[t] = ts2; __syncthreads();
  for(int off = 1; off < 256; off <<= 1){
    uint32_t y = (t >= off) ? sm[t - off] : 0u;
    __syncthreads(); sm[t] += y; __syncthreads();
  }
  uint32_t run2 = blockbase + sm[t] - ts2;
  #pragma unroll
  for(int k = 0; k < 8; k++){ uint32_t idx = base + k; if(idx < n) out[idx] = run2; run2 += xs[k]; }
  if(blockIdx.x == 0 && t == 0){
    if(MODE == 2){ sc[SC_C] = total; uint64_t cc = (uint64_t)total*(uint64_t)total; sc[SC_W] = (uint32_t)((cc + 31ull) >> 5); }
    if(MODE == 1){ sc[SC_U] = total; }
  }
}

// ---- cluster ids + wave-agg counts (total + per-shadow) + lazy zero psumS/bitmap ----
__global__ __launch_bounds__(256) void k_cluster_counts(const int* L, const uint32_t* rank_,
                       int* cluster_i, float* outC, uint32_t* counts, uint32_t* counts2,
                       float* psumS, uint32_t* bitmap, const uint32_t* sc){
  uint32_t C = sc[SC_C], W = sc[SC_W];
  uint32_t gid = blockIdx.x*256 + threadIdx.x, gs = gridDim.x*256;
  float4* p4 = (float4*)psumS;
  float4 z = make_float4(0.f,0.f,0.f,0.f);
  for(size_t j = gid; j < (size_t)NSHAD*C*(FDIM/4); j += gs) p4[j] = z;
  for(uint32_t j = gid; j < W; j += gs) bitmap[j] = 0u;
  int i = (int)gid;
  int lane = threadIdx.x & 63;
  int sh = (int)((gid >> 6) & (NSHAD2-1));
  int c = -1;
  if(i < N_NODES){
    c = (int)rank_[L[i]];
    cluster_i[i] = c;
    outC[i] = (float)c;
  }
  unsigned long long remaining = __ballot(i < N_NODES);
  while(remaining){
    int leader = __ffsll(remaining) - 1;
    int lc = __shfl(c, leader);
    unsigned long long grp = __ballot(c == lc) & remaining;
    if(lane == leader){
      uint32_t cnt = (uint32_t)__popcll(grp);
      atomicAdd(&counts[lc], cnt);                       // fire-and-forget (means)
      atomicAdd(&counts2[lc*NSHAD2 + sh], cnt);          // per-shadow capacity
    }
    remaining &= ~grp;
  }
}
// scatter via 16-shadow cursors: same grid geometry as k_cluster_counts => exact capacities
__global__ void k_scatter(const int* cluster_i, uint32_t* cursor2, uint32_t* order){
  uint32_t gid = blockIdx.x*256 + threadIdx.x;
  int i = (int)gid;
  int lane = threadIdx.x & 63;
  int sh = (int)((gid >> 6) & (NSHAD2-1));
  int c = (i < N_NODES) ? cluster_i[i] : -1;
  unsigned long long remaining = __ballot(i < N_NODES);
  while(remaining){
    int leader = __ffsll(remaining) - 1;
    int lc = __shfl(c, leader);
    unsigned long long grp = __ballot(c == lc) & remaining;
    int b = 0;
    if(lane == leader) b = (int)atomicAdd(&cursor2[lc*NSHAD2 + sh], (uint32_t)__popcll(grp));
    b = __shfl(b, leader);
    if((grp >> lane) & 1ull){
      uint32_t sub = (uint32_t)__popcll(grp & ((1ull << lane) - 1ull));
      order[(uint32_t)b + sub] = (uint32_t)i;
    }
    remaining &= ~grp;
  }
}

// ---- fused: segmented mean into 4-shadow psum (blocks < SGB; 64 rows/wave) |
//      edges+bitmap (rest) ----
__global__ __launch_bounds__(256) void k_seg_edges(const float* px, const uint32_t* order,
        const int* cluster_i, float* psumS, const int* src, const int* dst, uint32_t* sc,
        float* outE, uint32_t* kc, uint32_t* bitmap){
  if(blockIdx.x < SGB){
    int wave = (int)((blockIdx.x*256u + threadIdx.x) >> 6);
    int lane = threadIdx.x & 63;
    int start = wave * SROWS;
    if(start >= N_NODES) return;
    int cnt = N_NODES - start; if(cnt > SROWS) cnt = SROWS;
    size_t shadBase = (size_t)(wave & (NSHAD-1)) * (size_t)sc[SC_C] * FDIM;
    uint32_t ord0 = 0; int c0 = -1;
    if(lane < cnt){ ord0 = order[start + lane]; c0 = cluster_i[ord0]; }
    float ax = 0.f, ay = 0.f; int cur = -1;
    for(int r = 0; r < cnt; r++){
      uint32_t i = (uint32_t)__shfl((int)ord0, r);
      int c = __shfl(c0, r);
      if(c != cur){
        if(cur >= 0){
          atomicAdd(&psumS[shadBase + (size_t)cur*FDIM + 2*lane], ax);
          atomicAdd(&psumS[shadBase + (size_t)cur*FDIM + 2*lane + 1], ay);
        }
        cur = c; ax = 0.f; ay = 0.f;
      }
      float2 v = ((const float2*)(px + (size_t)i*FDIM))[lane];
      ax += v.x; ay += v.y;
    }
    if(cur >= 0){
      atomicAdd(&psumS[shadBase + (size_t)cur*FDIM + 2*lane], ax);
      atomicAdd(&psumS[shadBase + (size_t)cur*FDIM + 2*lane + 1], ay);
    }
  } else {
    __shared__ uint32_t wsum[4];
    int e = (blockIdx.x - SGB)*256 + threadIdx.x;
    int lane = threadIdx.x & 63;
    int wv = threadIdx.x >> 6;
    bool val = false;
    if(e < N_EDGES){
      int cu = cluster_i[src[e]];
      int cv = cluster_i[dst[e]];
      val = (cu != cv);
      outE[e] = val ? (float)cu : -1.0f;
      outE[N_EDGES + e] = val ? (float)cv : -1.0f;
      if(val){
        int a = cu < cv ? cu : cv, b = cu < cv ? cv : cu;
        uint32_t C = sc[SC_C];
        uint32_t key = (uint32_t)a * C + (uint32_t)b;
        kc[e] = key;
        atomicOr(&bitmap[key >> 5], 1u << (key & 31u));
      } else {
        kc[e] = 0xFFFFFFFFu;
      }
    }
    unsigned long long grp = __ballot(val);
    if(lane == 0) wsum[wv] = (uint32_t)__popcll(grp);
    __syncthreads();
    if(threadIdx.x == 0){
      uint32_t s = wsum[0] + wsum[1] + wsum[2] + wsum[3];
      if(s) atomicAdd(&sc[SC_VCNT], s);   // fire-and-forget (upper bound for dsum zeroing)
    }
  }
}

// ---- dual accumulate: 64 edges/wave, ballot + shfl-broadcast rank ----
__global__ __launch_bounds__(256) void k_dualacc(const float* dx, const uint32_t* kc,
                          const uint32_t* bitmap, const uint32_t* wpref,
                          float* dsum, uint32_t* dcnt){
  int wave = (int)((blockIdx.x*256u + threadIdx.x) >> 6);
  int lane = threadIdx.x & 63;
  int base = wave * 64;
  if(base >= N_EDGES) return;
  int e = base + lane;
  uint32_t key = (e < N_EDGES) ? kc[e] : 0xFFFFFFFFu;
  bool val = (key != 0xFFFFFFFFu);
  uint32_t r = 0;
  if(val){
    uint32_t wi = key >> 5, bi = key & 31u;
    r = wpref[wi] + __popc(bitmap[wi] & ((1u << bi) - 1u));
  }
  unsigned long long m = __ballot(val);
  while(m){
    int b = __ffsll(m) - 1;
    m &= m - 1;
    uint32_t ee = (uint32_t)(base + b);
    uint32_t rr = (uint32_t)__shfl((int)r, b);
    float2 v = ((const float2*)(dx + (size_t)ee*FDIM))[lane];
    atomicAdd(&dsum[(size_t)rr*FDIM + 2*lane], v.x);
    atomicAdd(&dsum[(size_t)rr*FDIM + 2*lane + 1], v.y);
    if(lane == 0) atomicAdd(&dcnt[rr], 1u);
  }
}
// ---- stream the full output region: shadow-summed means for live rows, zeros elsewhere ----
__global__ __launch_bounds__(256) void k_finalize(const float4* psumS, const uint32_t* counts,
        const float4* dsum, const uint32_t* dcnt, const uint32_t* sc, float4* out4){
  uint32_t C = sc[SC_C], U = sc[SC_U];
  size_t cs = (size_t)C * (FDIM/4);          // shadow stride in float4
  size_t gid = (size_t)blockIdx.x*256 + threadIdx.x;
  size_t gs = (size_t)gridDim.x*256;
  const size_t NP4 = (size_t)N_NODES*(FDIM/4);
  const size_t TOT4 = (size_t)(N_NODES + N_EDGES)*(FDIM/4);
  for(size_t j = gid; j < TOT4; j += gs){
    float4 v = make_float4(0.f,0.f,0.f,0.f);
    if(j < NP4){
      uint32_t r = (uint32_t)(j >> 5);
      if(r < C){
        v = psumS[j];
        #pragma unroll
        for(int s = 1; s < NSHAD; s++){
          float4 t = psumS[(size_t)s*cs + j];
          v.x += t.x; v.y += t.y; v.z += t.z; v.w += t.w;
        }
        float fc = (float)counts[r];
        v.x /= fc; v.y /= fc; v.z /= fc; v.w /= fc;
      }
    } else {
      size_t dj = j - NP4;
      uint32_t r = (uint32_t)(dj >> 5);
      if(r < U){
        v = dsum[dj];
        float fc = (float)dcnt[r];
        v.x /= fc; v.y /= fc; v.z /= fc; v.w /= fc;
      }
    }
    out4[j] = v;
  }
}

extern "C" void kernel_launch(void* const* d_in, const int* in_sizes, int n_in,
                              void* d_out, int out_size, void* d_ws, size_t ws_size,
                              hipStream_t stream){
  (void)in_sizes; (void)n_in; (void)out_size;
  const float* primal_x = (const float*)d_in[0];
  const float* dual_x   = (const float*)d_in[1];
  const float* att      = (const float*)d_in[2];
  const int*   pei      = (const int*)d_in[3];
  const int* src = pei;
  const int* dst = pei + N_EDGES;

  float* out  = (float*)d_out;
  float* outE = out + (size_t)(N_NODES + N_EDGES)*FDIM;   // (2, E)
  float* outC = outE + (size_t)2*N_EDGES;                 // (N,)

  uint32_t* w = (uint32_t*)d_ws;
  size_t words_avail = ws_size / 4;
  const size_t PSUMW = (size_t)NSHAD*CMAX*FDIM;            // 8.4M words
  const size_t CNT2W = (size_t)CMAX*NSHAD2;                // 262144 words
  const size_t FIXED = 64 + 1024 + (size_t)N_NODES + CNT2W
                     + TIECAP + 4*(size_t)N_NODES + CNT2W + 4*(size_t)WLCAP
                     + (size_t)N_EDGES + (size_t)N_EDGES   // kc + dcnt
                     + 4096
                     + PSUMW + (size_t)N_EDGES*FDIM;       // psumS + dsum
  size_t wcap = (words_avail > FIXED) ? (words_avail - FIXED)/2 : 4;
  if(wcap > 8388608) wcap = 8388608;   // supports C up to 16384
  wcap &= ~(size_t)3;

  size_t o = 0;
  uint32_t* sc      = w;               o += 64;
  uint32_t* hists   = w + o;           o += 1024;          // 3 x 256 used (+spare)
  size_t zero_words = o;                                    // zeroed per call (1088, mult of 4)
  uint32_t* counts  = w + o;           o += N_NODES;       // zeroed in k_seed
  uint32_t* counts2 = w + o;           o += CNT2W;         // zeroed in k_seed
  uint32_t* tieIdx  = w + o;           o += TIECAP;
  int* labels       = (int*)(w + o);   o += N_NODES;
  uint32_t* rank_   = w + o;           o += N_NODES;
  int* cluster_i    = (int*)(w + o);   o += N_NODES;
  uint32_t* order   = w + o;           o += N_NODES;
  uint32_t* cursor2 = w + o;           o += CNT2W;
  uint2* wl0        = (uint2*)(w + o); o += 2*(size_t)WLCAP;
  uint2* wl1        = (uint2*)(w + o); o += 2*(size_t)WLCAP;
  uint32_t* kc      = w + o;           o += N_EDGES;
  uint32_t* dcnt    = w + o;           o += N_EDGES;
  uint32_t* bsums   = w + o;           o += 4096;
  float* psumS      = (float*)(w + o); o += PSUMW;
  float* dsum       = (float*)(w + o); o += (size_t)N_EDGES*FDIM;
  uint32_t* bitmap  = w + o;           o += wcap;
  uint32_t* wpref   = w + o;           o += wcap;

  const int EB  = (N_EDGES + 255)/256;
  const int NB  = (N_NODES + 255)/256;
  const int WSB = (int)((wcap + 2047)/2048);           // <= 4096

  k_zero<<<2,256,0,stream>>>((uint4*)w, (uint32_t)(zero_words/4));
  // selection: 3 hist levels (24-bit prefix; prior digits recomputed in-block)
  k_hist8<1><<<HB,256,0,stream>>>(att, hists, labels);
  k_hist8<2><<<HB,256,0,stream>>>(att, hists, labels);
  k_hist8<3><<<HB,256,0,stream>>>(att, hists, labels);
  // CC: seed (+counts/counts2 zero) + relax ladder (ties fused into round 1)
  k_seed<<<EB,256,0,stream>>>(att, src, dst, hists, sc, tieIdx, labels, wl0, counts, counts2);
  for(int r = 1; r <= 8; ++r){
    uint2* win  = (r & 1) ? wl0 : wl1;
    uint2* wout = (r & 1) ? wl1 : wl0;
    k_relax<<<1024,256,0,stream>>>(win, wout, labels, sc, SC_WL0 + r - 1, SC_WL0 + r,
                                   tieIdx, att, src, dst, (r == 1) ? 1 : 0);
  }
  k_flatten_reduce<<<NSB,256,0,stream>>>(labels, bsums);
  k_scan_apply<2><<<NSB,256,0,stream>>>(counts, labels, bsums, NSB, rank_, sc);   // -> rank_, SC_C, SC_W
  k_cluster_counts<<<NB,256,0,stream>>>(labels, rank_, cluster_i, outC, counts, counts2,
                                        psumS, bitmap, sc);
  k_scan_reduce<3><<<CS2B,256,0,stream>>>(counts2, bsums, sc, dsum, dcnt);
  k_scan_apply<3><<<CS2B,256,0,stream>>>(counts2, labels, bsums, CS2B, cursor2, sc); // -> cursor2
  k_scatter<<<NB,256,0,stream>>>(cluster_i, cursor2, order);
  k_seg_edges<<<SGB + EB,256,0,stream>>>(primal_x, order, cluster_i, psumS,
                                         src, dst, sc, outE, kc, bitmap);
  k_scan_reduce<1><<<WSB,256,0,stream>>>(bitmap, bsums, sc, dsum, dcnt);          // + lazy zero dsum/dcnt
  k_scan_apply<1><<<WSB,256,0,stream>>>(bitmap, labels, bsums, WSB, wpref, sc);   // -> wpref, SC_U
  k_dualacc<<<EB,256,0,stream>>>(dual_x, kc, bitmap, wpref, dsum, dcnt);
  k_finalize<<<2048,256,0,stream>>>((const float4*)psumS, counts, (const float4*)dsum,
                                    dcnt, sc, (float4*)out);
}

// Round 17
// 508.662 us; speedup vs baseline: 3.5210x; 1.1595x over previous
//
#include <hip/hip_runtime.h>
#include <stdint.h>

// DualPrimalEdgePooling on MI355X — 21 dispatches.
// 3-level radix-select (24-bit prefix; full-key tie ranking fused into relax
// round 1) -> worklist min-label CC (jump fused via atomicMin, block-agg
// appends) -> flatten/rank scan -> cluster ids + IN-WAVE BITONIC-SORTED
// segmented mean into 4 shadow accumulators (no counting sort / scatter) ->
// edges+bitmap -> popcount-prefix dual ranking -> finalize streams output.
// NOTE: cooperative grid.sync measured ~95us/sync on MI355X — never mega-kernel.

#define N_NODES 200000
#define N_EDGES 600000
#define FDIM 128
#define NUM_POOL 300000u  // = E - NUM_KEEP

#define SC_NEEDEQ 3
#define SC_TIECNT 4
#define SC_C 5
#define SC_W 6
#define SC_U 7
#define SC_VCNT 8
#define SC_WL0 16        // per-round worklist counters: slots 16..24 (never reset)
#define TIECAP 4096
#define WLCAP 300800
#define HB 256           // hist grid blocks
#define NSB 98           // ceil(N/2048)
#define NSHAD 4          // psum shadow copies (atomic-depth divider)
#define CMAX 16384       // max clusters supported (bitmap/pair-key bound)

__device__ __forceinline__ uint32_t f2ou(float f){
  uint32_t b = __float_as_uint(f);
  return (b & 0x80000000u) ? ~b : (b | 0x80000000u);
}

// block-wide digit selection from a completed 256-bin histogram (blockDim=256)
static __device__ __forceinline__ void sel_level(const uint32_t* hist, uint32_t& target,
                                                 uint32_t& pfx, uint32_t* sm, uint32_t* res){
  int t = threadIdx.x;
  uint32_t cnt = hist[t];
  sm[t] = cnt; __syncthreads();
  for(int off = 1; off < 256; off <<= 1){
    uint32_t y = (t + off < 256) ? sm[t + off] : 0u;
    __syncthreads(); sm[t] += y; __syncthreads();
  }
  uint32_t suffix = sm[t];            // candidates with digit >= t
  uint32_t above  = suffix - cnt;
  if(above < target && target <= suffix){ res[0] = (uint32_t)t; res[1] = target - above; }
  __syncthreads();
  pfx = (pfx << 8) | res[0];
  target = res[1];
  __syncthreads();
}

// block-wide exclusive scan of one value per thread (blockDim=256); ends synced
static __device__ __forceinline__ uint32_t blk_excl(uint32_t v, uint32_t* sm, uint32_t& total){
  int t = threadIdx.x;
  sm[t] = v; __syncthreads();
  for(int off = 1; off < 256; off <<= 1){
    uint32_t y = (t >= off) ? sm[t - off] : 0u;
    __syncthreads(); sm[t] += y; __syncthreads();
  }
  total = sm[255];
  uint32_t incl = sm[t];
  __syncthreads();
  return incl - v;
}

// ---- tiny ws zero (sc + hists only) ----
__global__ __launch_bounds__(256) void k_zero(uint4* w4, uint32_t n4){
  uint32_t gid = blockIdx.x*256 + threadIdx.x;
  uint4 z = make_uint4(0u,0u,0u,0u);
  for(uint32_t j = gid; j < n4; j += gridDim.x*256) w4[j] = z;
}

// ---- selection: 3-level 8-bit radix histograms (24-bit prefix); prior digits
//      recomputed in-block ----
template<int LEVEL>
__global__ __launch_bounds__(256) void k_hist8(const float* att, uint32_t* hists, int* L){
  __shared__ uint32_t h[256];
  __shared__ uint32_t sm[256];
  __shared__ uint32_t res[2];
  h[threadIdx.x] = 0;
  if(LEVEL == 1){
    for(int i = blockIdx.x*256 + threadIdx.x; i < N_NODES; i += HB*256) L[i] = i;  // fused CC init
  }
  __syncthreads();
  uint32_t pfx = 0, target = NUM_POOL;
  #pragma unroll
  for(int l = 0; l < LEVEL-1; ++l) sel_level(hists + 256*l, target, pfx, sm, res);
  constexpr int SH1 = (LEVEL > 1) ? 8*(5-LEVEL) : 0;
  constexpr int SH2 = 8*(4-LEVEL);
  for(int e = blockIdx.x*256 + threadIdx.x; e < N_EDGES; e += HB*256){
    uint32_t u = f2ou(att[e]);
    bool ok = (LEVEL == 1) || ((u >> SH1) == pfx);
    if(ok) atomicAdd(&h[(u >> SH2) & 0xFFu], 1u);
  }
  __syncthreads();
  uint32_t c = h[threadIdx.x];
  if(c) atomicAdd(&hists[256*(LEVEL-1) + threadIdx.x], c);
}

// ---- seed: zero counts + full psumS; recompute 24-bit threshold in-block; pooled
//      edges ((u>>8) > T) hook + block-agg worklist append; prefix-tie edges recorded ----
__global__ __launch_bounds__(256) void k_seed(const float* att, const int* src, const int* dst,
                       const uint32_t* hists, uint32_t* sc, uint32_t* tieIdx, int* L, uint2* wl,
                       uint32_t* counts, float* psumS){
  __shared__ uint32_t sm[256];
  __shared__ uint32_t res[2];
  __shared__ uint32_t basesh;
  {
    uint32_t gid = blockIdx.x*256 + threadIdx.x;
    uint32_t gs = gridDim.x*256;
    for(uint32_t j = gid; j < N_NODES; j += gs) counts[j] = 0u;
    uint4* p4 = (uint4*)psumS;
    uint4 z = make_uint4(0u,0u,0u,0u);
    const uint32_t P4 = (uint32_t)NSHAD*CMAX*(FDIM/4);
    for(uint32_t j = gid; j < P4; j += gs) p4[j] = z;
  }
  uint32_t pfx = 0, target = NUM_POOL;
  #pragma unroll
  for(int l = 0; l < 3; ++l) sel_level(hists + 256*l, target, pfx, sm, res);
  if(blockIdx.x == 0 && threadIdx.x == 0) sc[SC_NEEDEQ] = target;
  uint32_t T = pfx;   // 24-bit prefix threshold
  int e = blockIdx.x*256 + threadIdx.x;
  bool app = false; int u = 0, v = 0;
  if(e < N_EDGES){
    uint32_t ub = f2ou(att[e]) >> 8;
    if(ub > T){
      u = src[e]; v = dst[e];
      if(u != v){
        int m = u < v ? u : v, hi = u ^ v ^ m;
        atomicMin(&L[hi], m);
        app = true;
      }
    } else if(ub == T){
      uint32_t p = atomicAdd(&sc[SC_TIECNT], 1u);
      if(p < TIECAP) tieIdx[p] = (uint32_t)e;
    }
  }
  uint32_t tot;
  uint32_t off = blk_excl(app ? 1u : 0u, sm, tot);
  if(threadIdx.x == 0 && tot) basesh = atomicAdd(&sc[SC_WL0], tot);
  __syncthreads();
  if(app) wl[basesh + off] = make_uint2((uint32_t)(u < v ? u : v), (uint32_t)(u > v ? u : v));
}

// relax + fused pointer jump + (round 1) fused tie selection.
__global__ __launch_bounds__(256) void k_relax(const uint2* wl_in, uint2* wl_out, int* L,
                       uint32_t* sc, int inSlot, int outSlot,
                       const uint32_t* tieIdx, const float* att,
                       const int* src, const int* dst, int doTies){
  __shared__ uint32_t sm[256];
  __shared__ uint32_t basesh;
  uint32_t n = sc[inSlot];
  for(uint32_t base = blockIdx.x*256u; base < n; base += gridDim.x*256u){
    uint32_t idx = base + threadIdx.x;
    bool active = idx < n;
    int lu = 0, lv = 0;
    if(active){
      uint2 ed = wl_in[idx];
      lu = L[ed.x]; lu = L[lu]; lu = L[lu]; lu = L[lu];
      lv = L[ed.y]; lv = L[lv]; lv = L[lv]; lv = L[lv];
      active = (lu != lv);
      if(active){
        int m = lu < lv ? lu : lv, hi = lu ^ lv ^ m;
        atomicMin(&L[hi], m);
      }
    }
    uint32_t tot;
    uint32_t off = blk_excl(active ? 1u : 0u, sm, tot);
    if(threadIdx.x == 0 && tot) basesh = atomicAdd(&sc[outSlot], tot);
    __syncthreads();
    if(active) wl_out[basesh + off] = make_uint2((uint32_t)(lu < lv ? lu : lv),
                                                 (uint32_t)(lu > lv ? lu : lv));
    __syncthreads();
  }
  if(doTies && blockIdx.x == 0){
    uint32_t m = sc[SC_TIECNT]; if(m > TIECAP) m = TIECAP;
    uint32_t need = sc[SC_NEEDEQ];
    for(uint32_t i0 = 0; i0 < m; i0 += 256){
      uint32_t i = i0 + threadIdx.x;
      bool app = false; int u = 0, v = 0;
      if(i < m){
        uint32_t mine = tieIdx[i];
        uint32_t ki = f2ou(att[mine]);
        uint32_t r = 0;
        for(uint32_t j = 0; j < m; j++){
          uint32_t oj = tieIdx[j];
          uint32_t kj = f2ou(att[oj]);
          r += (kj > ki || (kj == ki && oj < mine)) ? 1u : 0u;
        }
        if(r < need){   // stable argsort of -att: higher att first, then smaller index
          u = src[mine]; v = dst[mine];
          if(u != v){ int mm = u < v ? u : v, hi = u ^ v ^ mm; atomicMin(&L[hi], mm); app = true; }
        }
      }
      uint32_t tot;
      uint32_t off = blk_excl(app ? 1u : 0u, sm, tot);
      if(threadIdx.x == 0 && tot) basesh = atomicAdd(&sc[outSlot], tot);
      __syncthreads();
      if(app) wl_out[basesh + off] = make_uint2((uint32_t)(u < v ? u : v),
                                                (uint32_t)(u > v ? u : v));
      __syncthreads();
    }
  }
  if(n != 0){   // fused jump slice: monotone atomicMin => race-free vs concurrent hooks
    int i = blockIdx.x*256 + threadIdx.x;
    if(i < N_NODES){
      int v = L[i]; v = L[v]; v = L[v]; v = L[v];
      if(v < i) atomicMin(&L[i], v);
    }
  }
}
// flatten to roots + per-block root-count reduction (2048 nodes/block)
__global__ __launch_bounds__(256) void k_flatten_reduce(int* L, uint32_t* bsums){
  uint32_t base = blockIdx.x*2048u + threadIdx.x*8u;
  uint32_t s = 0;
  #pragma unroll
  for(int k = 0; k < 8; k++){
    uint32_t i = base + k;
    if(i < N_NODES){
      int p = L[i]; int q = L[p];
      while(q != p){ p = q; q = L[p]; }
      L[i] = p;
      s += (p == (int)i) ? 1u : 0u;
    }
  }
  __shared__ uint32_t sm[256];
  sm[threadIdx.x] = s; __syncthreads();
  for(int off = 128; off > 0; off >>= 1){
    if((int)threadIdx.x < off) sm[threadIdx.x] += sm[threadIdx.x + off];
    __syncthreads();
  }
  if(threadIdx.x == 0) bsums[blockIdx.x] = sm[0];
}

// ---- 2-kernel scans. MODE 1: popc(bitmap)->wpref (+SC_U). MODE 2: rootflag(L)->rank_
//      (+SC_C,SC_W). apply scans bsums in-LDS. ----
template<int MODE>
__device__ __forceinline__ uint32_t scan_n(const uint32_t* sc){
  if(MODE == 1) return sc[SC_W];
  return N_NODES;
}
template<int MODE>
__global__ __launch_bounds__(256) void k_scan_reduce(const uint32_t* in, uint32_t* bsums,
                       const uint32_t* sc, float* dsum, uint32_t* dcnt){
  uint32_t n = scan_n<MODE>(sc);
  if(MODE == 1){  // lazy-zero compact dual accumulators (VCNT rows >= U), vectorized
    uint32_t vc = sc[SC_VCNT];
    size_t gid = (size_t)blockIdx.x*256 + threadIdx.x, gs = (size_t)gridDim.x*256;
    float4* d4 = (float4*)dsum;
    float4 z = make_float4(0.f,0.f,0.f,0.f);
    for(size_t j = gid; j < (size_t)vc*(FDIM/4); j += gs) d4[j] = z;
    for(size_t j = gid; j < vc; j += gs) dcnt[j] = 0u;
  }
  uint32_t base = blockIdx.x*2048u + threadIdx.x*8u;
  uint32_t s = 0;
  #pragma unroll
  for(int k = 0; k < 8; k++){
    uint32_t idx = base + k;
    if(idx < n){ uint32_t v = in[idx]; if(MODE == 1) v = __popc(v); s += v; }
  }
  __shared__ uint32_t sm[256];
  sm[threadIdx.x] = s; __syncthreads();
  for(int off = 128; off > 0; off >>= 1){
    if((int)threadIdx.x < off) sm[threadIdx.x] += sm[threadIdx.x + off];
    __syncthreads();
  }
  if(threadIdx.x == 0) bsums[blockIdx.x] = sm[0];
}
template<int MODE>
__global__ __launch_bounds__(256) void k_scan_apply(const uint32_t* in, const int* L,
                       const uint32_t* bsums, int nb, uint32_t* out, uint32_t* sc){
  __shared__ uint32_t bs[4096];
  __shared__ uint32_t sm[256];
  int t = threadIdx.x;
  uint32_t n = scan_n<MODE>(sc);
  uint32_t loc[16]; uint32_t ls = 0;
  #pragma unroll
  for(int k = 0; k < 16; k++){ int idx = t*16 + k; uint32_t v = (idx < nb) ? bsums[idx] : 0u; loc[k] = v; ls += v; }
  sm[t] = ls; __syncthreads();
  for(int off = 1; off < 256; off <<= 1){
    uint32_t y = (t >= off) ? sm[t - off] : 0u;
    __syncthreads(); sm[t] += y; __syncthreads();
  }
  uint32_t total = sm[255];
  uint32_t run = sm[t] - ls;
  #pragma unroll
  for(int k = 0; k < 16; k++){ bs[t*16 + k] = run; run += loc[k]; }
  __syncthreads();
  uint32_t blockbase = bs[blockIdx.x];
  __syncthreads();
  uint32_t base = blockIdx.x*2048u + t*8u;
  uint32_t xs[8]; uint32_t ts2 = 0;
  #pragma unroll
  for(int k = 0; k < 8; k++){
    uint32_t idx = base + k; uint32_t v = 0;
    if(idx < n){
      if(MODE == 2) v = (L[idx] == (int)idx) ? 1u : 0u;
      else { v = in[idx]; if(MODE == 1) v = __popc(v); }
    }
    xs[k] = v; ts2 += v;
  }
  sm[t] = ts2; __syncthreads();
  for(int off = 1; off < 256; off <<= 1){
    uint32_t y = (t >= off) ? sm[t - off] : 0u;
    __syncthreads(); sm[t] += y; __syncthreads();
  }
  uint32_t run2 = blockbase + sm[t] - ts2;
  #pragma unroll
  for(int k = 0; k < 8; k++){ uint32_t idx = base + k; if(idx < n) out[idx] = run2; run2 += xs[k]; }
  if(blockIdx.x == 0 && t == 0){
    if(MODE == 2){ sc[SC_C] = total; uint64_t cc = (uint64_t)total*(uint64_t)total; sc[SC_W] = (uint32_t)((cc + 31ull) >> 5); }
    if(MODE == 1){ sc[SC_U] = total; }
  }
}

// ---- cluster ids + in-wave bitonic sort by cluster + run-flushed segmented mean
//      into 4-shadow psum + wave-agg counts + lazy zero bitmap.
//      N_NODES = 3125*64 exactly => waves are fully active or fully inactive. ----
__global__ __launch_bounds__(256) void k_cluster_seg(const int* L, const uint32_t* rank_,
                       const float* px, int* cluster_i, float* outC, uint32_t* counts,
                       float* psumS, uint32_t* bitmap, const uint32_t* sc){
  uint32_t W = sc[SC_W];
  uint32_t gid = blockIdx.x*256 + threadIdx.x, gs = gridDim.x*256;
  for(uint32_t j = gid; j < W; j += gs) bitmap[j] = 0u;
  int lane = (int)(threadIdx.x & 63);
  int wave = (int)(gid >> 6);
  int i = (int)gid;
  bool act = i < N_NODES;
  int key = 0x7FFFFFFF; uint32_t val = 0;
  if(act){
    int c = (int)rank_[L[i]];
    cluster_i[i] = c;
    outC[i] = (float)c;
    key = c; val = (uint32_t)i;
  }
  if(__ballot(act) == 0ull) return;   // fully-inactive tail wave
  // bitonic sort (key=cluster asc) across 64 lanes
  #pragma unroll
  for(int k = 2; k <= 64; k <<= 1){
    #pragma unroll
    for(int j = k >> 1; j > 0; j >>= 1){
      int ok = __shfl_xor(key, j);
      uint32_t ov = (uint32_t)__shfl_xor((int)val, j);
      bool up = ((lane & k) == 0);
      bool keepMin = (((lane & j) == 0) == up);
      if((key > ok) == keepMin){ key = ok; val = ov; }
    }
  }
  size_t shadBase = (size_t)(wave & (NSHAD-1)) * (size_t)sc[SC_C] * FDIM;
  float ax = 0.f, ay = 0.f; int cur = -1; uint32_t runLen = 0;
  for(int r = 0; r < 64; r++){
    int c = __shfl(key, r);
    uint32_t ii = (uint32_t)__shfl((int)val, r);
    if(c != cur){
      if(cur >= 0){
        atomicAdd(&psumS[shadBase + (size_t)cur*FDIM + 2*lane], ax);
        atomicAdd(&psumS[shadBase + (size_t)cur*FDIM + 2*lane + 1], ay);
        if(lane == 0) atomicAdd(&counts[cur], runLen);
      }
      cur = c; ax = 0.f; ay = 0.f; runLen = 0;
    }
    float2 v = ((const float2*)(px + (size_t)ii*FDIM))[lane];
    ax += v.x; ay += v.y; runLen++;
  }
  if(cur >= 0){
    atomicAdd(&psumS[shadBase + (size_t)cur*FDIM + 2*lane], ax);
    atomicAdd(&psumS[shadBase + (size_t)cur*FDIM + 2*lane + 1], ay);
    if(lane == 0) atomicAdd(&counts[cur], runLen);
  }
}

// ---- edges: rebuilt edge index + pair-key bitmap; one count atomic per block ----
__global__ __launch_bounds__(256) void k_edges(const int* src, const int* dst,
        const int* cluster_i, uint32_t* sc, float* outE, uint32_t* kc, uint32_t* bitmap){
  __shared__ uint32_t wsum[4];
  int e = blockIdx.x*256 + threadIdx.x;
  int lane = threadIdx.x & 63;
  int wv = threadIdx.x >> 6;
  bool val = false;
  if(e < N_EDGES){
    int cu = cluster_i[src[e]];
    int cv = cluster_i[dst[e]];
    val = (cu != cv);
    outE[e] = val ? (float)cu : -1.0f;
    outE[N_EDGES + e] = val ? (float)cv : -1.0f;
    if(val){
      int a = cu < cv ? cu : cv, b = cu < cv ? cv : cu;
      uint32_t C = sc[SC_C];
      uint32_t key = (uint32_t)a * C + (uint32_t)b;
      kc[e] = key;
      atomicOr(&bitmap[key >> 5], 1u << (key & 31u));
    } else {
      kc[e] = 0xFFFFFFFFu;
    }
  }
  unsigned long long grp = __ballot(val);
  if(lane == 0) wsum[wv] = (uint32_t)__popcll(grp);
  __syncthreads();
  if(threadIdx.x == 0){
    uint32_t s = wsum[0] + wsum[1] + wsum[2] + wsum[3];
    if(s) atomicAdd(&sc[SC_VCNT], s);   // fire-and-forget (upper bound for dsum zeroing)
  }
}

// ---- dual accumulate: 64 edges/wave, ballot + shfl-broadcast rank ----
__global__ __launch_bounds__(256) void k_dualacc(const float* dx, const uint32_t* kc,
                          const uint32_t* bitmap, const uint32_t* wpref,
                          float* dsum, uint32_t* dcnt){
  int wave = (int)((blockIdx.x*256u + threadIdx.x) >> 6);
  int lane = threadIdx.x & 63;
  int base = wave * 64;
  if(base >= N_EDGES) return;
  int e = base + lane;
  uint32_t key = (e < N_EDGES) ? kc[e] : 0xFFFFFFFFu;
  bool val = (key != 0xFFFFFFFFu);
  uint32_t r = 0;
  if(val){
    uint32_t wi = key >> 5, bi = key & 31u;
    r = wpref[wi] + __popc(bitmap[wi] & ((1u << bi) - 1u));
  }
  unsigned long long m = __ballot(val);
  while(m){
    int b = __ffsll(m) - 1;
    m &= m - 1;
    uint32_t ee = (uint32_t)(base + b);
    uint32_t rr = (uint32_t)__shfl((int)r, b);
    float2 v = ((const float2*)(dx + (size_t)ee*FDIM))[lane];
    atomicAdd(&dsum[(size_t)rr*FDIM + 2*lane], v.x);
    atomicAdd(&dsum[(size_t)rr*FDIM + 2*lane + 1], v.y);
    if(lane == 0) atomicAdd(&dcnt[rr], 1u);
  }
}
// ---- stream the full output region: shadow-summed means for live rows, zeros elsewhere ----
__global__ __launch_bounds__(256) void k_finalize(const float4* psumS, const uint32_t* counts,
        const float4* dsum, const uint32_t* dcnt, const uint32_t* sc, float4* out4){
  uint32_t C = sc[SC_C], U = sc[SC_U];
  size_t cs = (size_t)C * (FDIM/4);          // shadow stride in float4
  size_t gid = (size_t)blockIdx.x*256 + threadIdx.x;
  size_t gs = (size_t)gridDim.x*256;
  const size_t NP4 = (size_t)N_NODES*(FDIM/4);
  const size_t TOT4 = (size_t)(N_NODES + N_EDGES)*(FDIM/4);
  for(size_t j = gid; j < TOT4; j += gs){
    float4 v = make_float4(0.f,0.f,0.f,0.f);
    if(j < NP4){
      uint32_t r = (uint32_t)(j >> 5);
      if(r < C){
        v = psumS[j];
        #pragma unroll
        for(int s = 1; s < NSHAD; s++){
          float4 t = psumS[(size_t)s*cs + j];
          v.x += t.x; v.y += t.y; v.z += t.z; v.w += t.w;
        }
        float fc = (float)counts[r];
        v.x /= fc; v.y /= fc; v.z /= fc; v.w /= fc;
      }
    } else {
      size_t dj = j - NP4;
      uint32_t r = (uint32_t)(dj >> 5);
      if(r < U){
        v = dsum[dj];
        float fc = (float)dcnt[r];
        v.x /= fc; v.y /= fc; v.z /= fc; v.w /= fc;
      }
    }
    out4[j] = v;
  }
}

extern "C" void kernel_launch(void* const* d_in, const int* in_sizes, int n_in,
                              void* d_out, int out_size, void* d_ws, size_t ws_size,
                              hipStream_t stream){
  (void)in_sizes; (void)n_in; (void)out_size;
  const float* primal_x = (const float*)d_in[0];
  const float* dual_x   = (const float*)d_in[1];
  const float* att      = (const float*)d_in[2];
  const int*   pei      = (const int*)d_in[3];
  const int* src = pei;
  const int* dst = pei + N_EDGES;

  float* out  = (float*)d_out;
  float* outE = out + (size_t)(N_NODES + N_EDGES)*FDIM;   // (2, E)
  float* outC = outE + (size_t)2*N_EDGES;                 // (N,)

  uint32_t* w = (uint32_t*)d_ws;
  size_t words_avail = ws_size / 4;
  const size_t PSUMW = (size_t)NSHAD*CMAX*FDIM;            // 8.4M words
  const size_t FIXED = 64 + 1024 + (size_t)N_NODES
                     + TIECAP + 3*(size_t)N_NODES + 4*(size_t)WLCAP
                     + (size_t)N_EDGES + (size_t)N_EDGES   // kc + dcnt
                     + 4096
                     + PSUMW + (size_t)N_EDGES*FDIM;       // psumS + dsum
  size_t wcap = (words_avail > FIXED) ? (words_avail - FIXED)/2 : 4;
  if(wcap > 8388608) wcap = 8388608;   // supports C up to 16384
  wcap &= ~(size_t)3;

  size_t o = 0;
  uint32_t* sc      = w;               o += 64;
  uint32_t* hists   = w + o;           o += 1024;          // 3 x 256 used (+spare)
  size_t zero_words = o;                                    // zeroed per call (1088, mult of 4)
  uint32_t* counts  = w + o;           o += N_NODES;       // zeroed in k_seed
  uint32_t* tieIdx  = w + o;           o += TIECAP;
  int* labels       = (int*)(w + o);   o += N_NODES;
  uint32_t* rank_   = w + o;           o += N_NODES;
  int* cluster_i    = (int*)(w + o);   o += N_NODES;
  uint2* wl0        = (uint2*)(w + o); o += 2*(size_t)WLCAP;
  uint2* wl1        = (uint2*)(w + o); o += 2*(size_t)WLCAP;
  uint32_t* kc      = w + o;           o += N_EDGES;
  uint32_t* dcnt    = w + o;           o += N_EDGES;
  uint32_t* bsums   = w + o;           o += 4096;
  float* psumS      = (float*)(w + o); o += PSUMW;         // zeroed in k_seed
  float* dsum       = (float*)(w + o); o += (size_t)N_EDGES*FDIM;
  uint32_t* bitmap  = w + o;           o += wcap;
  uint32_t* wpref   = w + o;           o += wcap;

  const int EB  = (N_EDGES + 255)/256;
  const int NB  = (N_NODES + 255)/256;
  const int WSB = (int)((wcap + 2047)/2048);           // <= 4096

  k_zero<<<2,256,0,stream>>>((uint4*)w, (uint32_t)(zero_words/4));
  // selection: 3 hist levels (24-bit prefix; prior digits recomputed in-block)
  k_hist8<1><<<HB,256,0,stream>>>(att, hists, labels);
  k_hist8<2><<<HB,256,0,stream>>>(att, hists, labels);
  k_hist8<3><<<HB,256,0,stream>>>(att, hists, labels);
  // CC: seed (+counts/psumS zero) + relax ladder (ties fused into round 1)
  k_seed<<<EB,256,0,stream>>>(att, src, dst, hists, sc, tieIdx, labels, wl0, counts, psumS);
  for(int r = 1; r <= 8; ++r){
    uint2* win  = (r & 1) ? wl0 : wl1;
    uint2* wout = (r & 1) ? wl1 : wl0;
    k_relax<<<1024,256,0,stream>>>(win, wout, labels, sc, SC_WL0 + r - 1, SC_WL0 + r,
                                   tieIdx, att, src, dst, (r == 1) ? 1 : 0);
  }
  k_flatten_reduce<<<NSB,256,0,stream>>>(labels, bsums);
  k_scan_apply<2><<<NSB,256,0,stream>>>(counts, labels, bsums, NSB, rank_, sc);   // -> rank_, SC_C, SC_W
  // cluster ids + in-wave sorted segmented mean (+bitmap zero)
  k_cluster_seg<<<NB,256,0,stream>>>(labels, rank_, primal_x, cluster_i, outC,
                                     counts, psumS, bitmap, sc);
  k_edges<<<EB,256,0,stream>>>(src, dst, cluster_i, sc, outE, kc, bitmap);
  k_scan_reduce<1><<<WSB,256,0,stream>>>(bitmap, bsums, sc, dsum, dcnt);          // + lazy zero dsum/dcnt
  k_scan_apply<1><<<WSB,256,0,stream>>>(bitmap, labels, bsums, WSB, wpref, sc);   // -> wpref, SC_U
  k_dualacc<<<EB,256,0,stream>>>(dual_x, kc, bitmap, wpref, dsum, dcnt);
  k_finalize<<<2048,256,0,stream>>>((const float4*)psumS, counts, (const float4*)dsum,
                                    dcnt, sc, (float4*)out);
}